// Round 12
// baseline (1821.875 us; speedup 1.0000x reference)
//
#include <hip/hip_runtime.h>
#include <math.h>

#define NROWS  65536
#define DDIM   256
#define KCODES 512
#define BM     32
#define BD     16
#define NTH    512
#define NSTAGE 3
#define MARGIN  1.0e-2f
#define MAXFLAG 8192

// ---- np.sum(x*x,-1) model: numpy dispatched pairwise_sum, AVX512F width-16 ----
// loops_arithm_fp.dispatch.c.src FLOAT_pairwise_sum, avx512f target (EPYC host):
// n=256 -> two 128-blocks (blk0+blk1). Each 128-block: 4 vector accumulators
// (width 16), unroll 4 vectors/iter (64 elems), 2 iterations:
//   P[j][l] = fl( a[16j+l]^2 + a[64+16j+l]^2 )     (init add to zero exact)
// combine lanewise (P0+P1)+(P2+P3) -> v[16];
// npyv_sum_f32 = _mm512_reduce_add_ps tree:
//   s1[l]=v[l]+v[l+8]; s2[l]=s1[l]+s1[l+4]; s3=(s2[0]+s2[2], s2[1]+s2[3]);
//   r = s3[0]+s3[1].
// Squares from the separate multiply ufunc temp: each mul rounded alone.
__device__ __forceinline__ float np_sumsq256(const float* p) {
#pragma clang fp contract(off)
  float blk[2];
#pragma unroll
  for (int b = 0; b < 2; ++b) {
    const float* a = p + b * 128;
    float v[16];
#pragma unroll
    for (int l = 0; l < 16; ++l) {
      float p0a = a[l] * a[l];
      float p0b = a[64 + l] * a[64 + l];
      float P0 = p0a + p0b;
      float p1a = a[16 + l] * a[16 + l];
      float p1b = a[80 + l] * a[80 + l];
      float P1 = p1a + p1b;
      float p2a = a[32 + l] * a[32 + l];
      float p2b = a[96 + l] * a[96 + l];
      float P2 = p2a + p2b;
      float p3a = a[48 + l] * a[48 + l];
      float p3b = a[112 + l] * a[112 + l];
      float P3 = p3a + p3b;
      v[l] = (P0 + P1) + (P2 + P3);
    }
    float s1[8];
#pragma unroll
    for (int l = 0; l < 8; ++l) s1[l] = v[l] + v[l + 8];
    float s2[4];
#pragma unroll
    for (int l = 0; l < 4; ++l) s2[l] = s1[l] + s1[l + 4];
    float s3_0 = s2[0] + s2[2];
    float s3_1 = s2[1] + s2[3];
    blk[b] = s3_0 + s3_1;
  }
  return blk[0] + blk[1];
}

// ---- np c_einsum dot model: einsum_sumprod.c.src, npyv baseline SSE3 ----
// (einsum is baseline-only, NOT dispatched.) ONE width-4 vaccum; per 16-elem
// iter, chained muladds in REVERSE sub-chunk order (a3 first):
//   v[l] = a0*b0 + (a1*b1 + (a2*b2 + (a3*b3 + v[l])))
// npyv_muladd on SSE3 = separate mul+add roundings (no FMA).
// Finish: npyv_sum_f32 (SSE3 hadd x2) = (v0+v1)+(v2+v3).
__device__ __forceinline__ float np_einsum_dot256(const float* __restrict__ x,
                                                  const float* __restrict__ c) {
#pragma clang fp contract(off)
  float v[4] = {0.f, 0.f, 0.f, 0.f};
  for (int t = 0; t < 16; ++t) {
    const float* a = x + t * 16;
    const float* b = c + t * 16;
#pragma unroll
    for (int l = 0; l < 4; ++l) {
      float ab3 = a[12 + l] * b[12 + l] + v[l];
      float ab2 = a[8 + l] * b[8 + l] + ab3;
      float ab1 = a[4 + l] * b[4 + l] + ab2;
      v[l] = a[0 + l] * b[0 + l] + ab1;
    }
  }
  return (v[0] + v[1]) + (v[2] + v[3]);
}

// ---------------- codebook norms, np-bitwise ----------------
__global__ void cc_np_k(const float* __restrict__ c0, const float* __restrict__ c1,
                        const float* __restrict__ c2, float* __restrict__ cc) {
  int t = blockIdx.x * blockDim.x + threadIdx.x;
  if (t >= NSTAGE * KCODES) return;
  const float* cb = (t < KCODES) ? c0 : (t < 2 * KCODES ? c1 : c2);
  cc[t] = np_sumsq256(cb + (size_t)(t & (KCODES - 1)) * DDIM);
}

// ---------------- fast distance + top-2 + flag ----------------
// Block: 512 thr = 8 waves, BM=32 rows vs 512 codes. Wave w: rows w*4..+3;
// lane l: codes {l*4..+3, 256+l*4..+3}. Dots: sequential f32 FMA (fast path).
// Rows with top-2 gap < MARGIN are flagged for np-bitwise refine.
__global__ __launch_bounds__(NTH) void fast_k(
    const float* __restrict__ data, const float* __restrict__ cb,
    const float* __restrict__ cbA, const float* __restrict__ cbB,
    const int* __restrict__ idxA, const int* __restrict__ idxB,
    const float* __restrict__ ccs, int stage,
    int* __restrict__ idx_out, unsigned int* __restrict__ flagcnt,
    int* __restrict__ flagrows) {
  __shared__ float cbl[BD][KCODES];
  __shared__ float rl[BD][BM];
  __shared__ float ccl[KCODES];

  const int tid = threadIdx.x;
  const int lane = tid & 63;
  const int w = tid >> 6;
  const int rowbase = blockIdx.x * BM;

  ccl[tid] = ccs[tid];

  float acc[4][8];
#pragma unroll
  for (int m = 0; m < 4; ++m)
#pragma unroll
    for (int q = 0; q < 8; ++q) acc[m][q] = 0.0f;

  for (int c = 0; c < DDIM / BD; ++c) {
    const int d0 = c * BD;
    __syncthreads();
    {
      const float4* src = (const float4*)(cb + (size_t)tid * DDIM + d0);
#pragma unroll
      for (int j = 0; j < 4; ++j) {
        float4 v = src[j];
        cbl[4 * j + 0][tid] = v.x;
        cbl[4 * j + 1][tid] = v.y;
        cbl[4 * j + 2][tid] = v.z;
        cbl[4 * j + 3][tid] = v.w;
      }
    }
    if (tid < BM * 4) {
#pragma clang fp contract(off)
      const int rrow = tid >> 2;
      const int dsub = (tid & 3) * 4;
      const int r = rowbase + rrow;
      const size_t base = (size_t)r * DDIM + d0 + dsub;
      float4 dv = *(const float4*)(data + base);
      float x1[4] = {dv.x, dv.y, dv.z, dv.w};
      float res[4];
      if (stage == 0) {
#pragma unroll
        for (int j = 0; j < 4; ++j) res[j] = x1[j];
      } else {
        const int iA = idxA[r];
        float4 av = *(const float4*)(cbA + (size_t)iA * DDIM + d0 + dsub);
        float af[4] = {av.x, av.y, av.z, av.w};
        float a[4];
#pragma unroll
        for (int j = 0; j < 4; ++j) a[j] = x1[j] + (af[j] - x1[j]);
        if (stage == 2) {
          const int iB = idxB[r];
          float4 bv = *(const float4*)(cbB + (size_t)iB * DDIM + d0 + dsub);
          float bf[4] = {bv.x, bv.y, bv.z, bv.w};
#pragma unroll
          for (int j = 0; j < 4; ++j) {
            float x2 = x1[j] - a[j];
            float qst2 = x2 + (bf[j] - x2);
            a[j] = a[j] + qst2;
          }
        }
#pragma unroll
        for (int j = 0; j < 4; ++j) res[j] = x1[j] - a[j];
      }
      rl[dsub + 0][rrow] = res[0];
      rl[dsub + 1][rrow] = res[1];
      rl[dsub + 2][rrow] = res[2];
      rl[dsub + 3][rrow] = res[3];
    }
    __syncthreads();
#pragma unroll
    for (int dd = 0; dd < BD; ++dd) {
      float4 rv4 = *(const float4*)&rl[dd][w * 4];
      float4 ca = *(const float4*)&cbl[dd][lane * 4];
      float4 cbb = *(const float4*)&cbl[dd][256 + lane * 4];
      float rv[4] = {rv4.x, rv4.y, rv4.z, rv4.w};
      float cv[8] = {ca.x, ca.y, ca.z, ca.w, cbb.x, cbb.y, cbb.z, cbb.w};
#pragma unroll
      for (int m = 0; m < 4; ++m)
#pragma unroll
        for (int q = 0; q < 8; ++q)
          acc[m][q] = fmaf(rv[m], cv[q], acc[m][q]);
    }
  }

#pragma unroll
  for (int m = 0; m < 4; ++m) {
    float v1 = 3.0e38f, v2 = 3.0e38f;
    int i1 = 0x7fffffff;
#pragma unroll
    for (int q = 0; q < 8; ++q) {
      int k = (q < 4) ? (lane * 4 + q) : (256 + lane * 4 + (q - 4));
      float d = __fsub_rn(ccl[k], 2.0f * acc[m][q]);
      if (d < v1 || (d == v1 && k < i1)) { v2 = v1; v1 = d; i1 = k; }
      else if (d < v2) v2 = d;
    }
#pragma unroll
    for (int off = 1; off < 64; off <<= 1) {
      float ov1 = __shfl_xor(v1, off, 64);
      int oi1 = __shfl_xor(i1, off, 64);
      float ov2 = __shfl_xor(v2, off, 64);
      float worst = fmaxf(v1, ov1);
      v2 = fminf(fminf(v2, ov2), worst);
      if (ov1 < v1 || (ov1 == v1 && oi1 < i1)) { v1 = ov1; i1 = oi1; }
    }
    if (lane == 0) {
      int row = rowbase + w * 4 + m;
      idx_out[row] = i1;
      if (v2 - v1 < MARGIN) {
        unsigned pos = atomicAdd(flagcnt, 1u);
        if (pos < MAXFLAG) flagrows[pos] = row;
      }
    }
  }
}

// ---------------- np-bitwise refine for flagged rows ----------------
// Transliterated composition: d = fl( fl(xx - fl(2*dot)) + cc );
// xx/cc = AVX512F dispatched pairwise model; dot = einsum SSE3 model.
__global__ __launch_bounds__(256) void refine_k(
    const float* __restrict__ data, const float* __restrict__ cb,
    const float* __restrict__ cbA, const float* __restrict__ cbB,
    const int* __restrict__ idxA, const int* __restrict__ idxB,
    const float* __restrict__ ccs, int stage,
    const unsigned int* __restrict__ flagcnt, const int* __restrict__ flagrows,
    int* __restrict__ idx_out) {
  __shared__ float rl[DDIM];
  __shared__ float xxs;
  __shared__ float red_v[256];
  __shared__ int red_i[256];

  unsigned int n = *flagcnt;
  if (n > MAXFLAG) n = MAXFLAG;
  const int tid = threadIdx.x;

  for (unsigned f = blockIdx.x; f < n; f += gridDim.x) {
    const int r = flagrows[f];
    if (tid < 64) {
#pragma clang fp contract(off)
      const size_t base = (size_t)r * DDIM + tid * 4;
      float4 dv = *(const float4*)(data + base);
      float x1[4] = {dv.x, dv.y, dv.z, dv.w};
      float res[4];
      if (stage == 0) {
#pragma unroll
        for (int j = 0; j < 4; ++j) res[j] = x1[j];
      } else {
        const int iA = idxA[r];
        float4 av = *(const float4*)(cbA + (size_t)iA * DDIM + tid * 4);
        float af[4] = {av.x, av.y, av.z, av.w};
        float a[4];
#pragma unroll
        for (int j = 0; j < 4; ++j) a[j] = x1[j] + (af[j] - x1[j]);
        if (stage == 2) {
          const int iB = idxB[r];
          float4 bv = *(const float4*)(cbB + (size_t)iB * DDIM + tid * 4);
          float bf[4] = {bv.x, bv.y, bv.z, bv.w};
#pragma unroll
          for (int j = 0; j < 4; ++j) {
            float x2 = x1[j] - a[j];
            float qst2 = x2 + (bf[j] - x2);
            a[j] = a[j] + qst2;
          }
        }
#pragma unroll
        for (int j = 0; j < 4; ++j) res[j] = x1[j] - a[j];
      }
#pragma unroll
      for (int j = 0; j < 4; ++j) rl[tid * 4 + j] = res[j];
    }
    __syncthreads();
    if (tid == 0) xxs = np_sumsq256(rl);
    __syncthreads();

    float bv = 3.0e38f;
    int bi = 0x7fffffff;
#pragma unroll
    for (int h = 0; h < 2; ++h) {
      const int k = tid + h * 256;
      float d;
      {
#pragma clang fp contract(off)
        float dot = np_einsum_dot256(rl, cb + (size_t)k * DDIM);
        float t1 = xxs - 2.0f * dot;
        d = t1 + ccs[k];
      }
      if (d < bv || (d == bv && k < bi)) { bv = d; bi = k; }
    }
    red_v[tid] = bv;
    red_i[tid] = bi;
    __syncthreads();
    for (int sgap = 128; sgap > 0; sgap >>= 1) {
      if (tid < sgap) {
        float o = red_v[tid + sgap];
        int oi = red_i[tid + sgap];
        if (o < red_v[tid] || (o == red_v[tid] && oi < red_i[tid])) {
          red_v[tid] = o;
          red_i[tid] = oi;
        }
      }
      __syncthreads();
    }
    if (tid == 0) idx_out[r] = red_i[0];
    __syncthreads();
  }
}

// ---------------- final pass: quantized, one-hots (incl zeros), hist, loss ----
__global__ __launch_bounds__(256) void final_k(
    const float* __restrict__ data, const float* __restrict__ cb0,
    const float* __restrict__ cb1, const float* __restrict__ cb2,
    const int* __restrict__ idx0, const int* __restrict__ idx1,
    const int* __restrict__ idx2, float* __restrict__ quant,
    float* __restrict__ enc0, float* __restrict__ enc1,
    float* __restrict__ enc2, double* __restrict__ loss_sum,
    unsigned int* __restrict__ hist) {
  const int lane = threadIdx.x & 63;
  const int r = blockIdx.x * 4 + (threadIdx.x >> 6);
  const int i0 = idx0[r], i1 = idx1[r], i2 = idx2[r];
  const size_t base = (size_t)r * DDIM + lane * 4;
  float4 dv = *(const float4*)(data + base);
  float4 c0v = *(const float4*)(cb0 + (size_t)i0 * DDIM + lane * 4);
  float4 c1v = *(const float4*)(cb1 + (size_t)i1 * DDIM + lane * 4);
  float4 c2v = *(const float4*)(cb2 + (size_t)i2 * DDIM + lane * 4);
  float df[4] = {dv.x, dv.y, dv.z, dv.w};
  float q0f[4] = {c0v.x, c0v.y, c0v.z, c0v.w};
  float q1f[4] = {c1v.x, c1v.y, c1v.z, c1v.w};
  float q2f[4] = {c2v.x, c2v.y, c2v.z, c2v.w};
  float qout[4];
  double lsum = 0.0;
  {
#pragma clang fp contract(off)
#pragma unroll
    for (int j = 0; j < 4; ++j) {
      float x1 = df[j];
      float d1 = q0f[j] - x1;
      float qst1 = x1 + d1;
      float a1 = qst1;
      float x2 = x1 - a1;
      float d2 = q1f[j] - x2;
      float qst2 = x2 + d2;
      float a2 = a1 + qst2;
      float x3 = x1 - a2;
      float d3 = q2f[j] - x3;
      float qst3 = x3 + d3;
      float a3 = a2 + qst3;
      qout[j] = a3;
      lsum += (double)d1 * d1 + (double)d2 * d2 + (double)d3 * d3;
    }
  }
  float4 qv = {qout[0], qout[1], qout[2], qout[3]};
  *(float4*)(quant + base) = qv;

  // one-hot rows (zeros + single 1), 8 cols per lane per enc
  const int kb = lane * 8;
  float* eptr[3] = {enc0, enc1, enc2};
  int eidx[3] = {i0, i1, i2};
#pragma unroll
  for (int e = 0; e < 3; ++e) {
    float4 u0, u1;
    u0.x = (kb + 0 == eidx[e]) ? 1.0f : 0.0f;
    u0.y = (kb + 1 == eidx[e]) ? 1.0f : 0.0f;
    u0.z = (kb + 2 == eidx[e]) ? 1.0f : 0.0f;
    u0.w = (kb + 3 == eidx[e]) ? 1.0f : 0.0f;
    u1.x = (kb + 4 == eidx[e]) ? 1.0f : 0.0f;
    u1.y = (kb + 5 == eidx[e]) ? 1.0f : 0.0f;
    u1.z = (kb + 6 == eidx[e]) ? 1.0f : 0.0f;
    u1.w = (kb + 7 == eidx[e]) ? 1.0f : 0.0f;
    float* dst = eptr[e] + (size_t)r * KCODES + kb;
    *(float4*)(dst) = u0;
    *(float4*)(dst + 4) = u1;
  }

#pragma unroll
  for (int off = 1; off < 64; off <<= 1) lsum += __shfl_xor(lsum, off, 64);
  if (lane == 0) {
    atomicAdd(loss_sum, lsum);
    atomicAdd(&hist[i0], 1u);
  } else if (lane == 1) {
    atomicAdd(&hist[KCODES + i1], 1u);
  } else if (lane == 2) {
    atomicAdd(&hist[2 * KCODES + i2], 1u);
  }
}

// ---------------- scalars ----------------
__global__ void finalize_k(const unsigned int* __restrict__ hist,
                           const double* __restrict__ loss_sum,
                           float* __restrict__ out_scalars) {
  int lane = threadIdx.x;  // 64 threads
  double te = 0.0;
  for (int s = 0; s < NSTAGE; ++s) {
    double e = 0.0;
    for (int j = 0; j < KCODES / 64; ++j) {
      int k = j * 64 + lane;
      float pf = (float)hist[s * KCODES + k] * (1.0f / 65536.0f);  // exact
      float sf = __fadd_rn(pf, 1e-10f);
      e += (double)pf * log((double)sf);
    }
#pragma unroll
    for (int off = 1; off < 64; off <<= 1) e += __shfl_xor(e, off, 64);
    te += -e;
  }
  if (lane == 0) {
    double tl = 1.25 * loss_sum[0] * (1.0 / 16777216.0);  // (q+0.25e)/(N*D)
    out_scalars[0] = (float)tl;
    out_scalars[1] = (float)te;
  }
}

extern "C" void kernel_launch(void* const* d_in, const int* in_sizes, int n_in,
                              void* d_out, int out_size, void* d_ws, size_t ws_size,
                              hipStream_t stream) {
  const float* data = (const float*)d_in[0];
  const float* cb0 = (const float*)d_in[1];
  const float* cb1 = (const float*)d_in[2];
  const float* cb2 = (const float*)d_in[3];
  const float* cbs[3] = {cb0, cb1, cb2};
  float* out = (float*)d_out;
  float* quant = out;
  float* enc0 = out + (size_t)NROWS * DDIM;
  float* enc1 = enc0 + (size_t)NROWS * KCODES;
  float* enc2 = enc1 + (size_t)NROWS * KCODES;
  float* out_scalars = enc2 + (size_t)NROWS * KCODES;

  // ws: [0) loss f64 | 64) hist u32x1536 | 6272) flagcnt u32x3 |
  //     6400) flagrows i32[3][MAXFLAG] | 104960) cc f32x1536 | 111616) idx i32[3][N]
  double* loss_sum = (double*)d_ws;
  unsigned int* hist = (unsigned int*)((char*)d_ws + 64);
  unsigned int* flagcnt = (unsigned int*)((char*)d_ws + 6272);
  int* flagrows = (int*)((char*)d_ws + 6400);
  float* cc = (float*)((char*)d_ws + 104960);
  int* idx0 = (int*)((char*)d_ws + 111616);
  int* idx1 = idx0 + NROWS;
  int* idx2 = idx1 + NROWS;
  int* idxs[3] = {idx0, idx1, idx2};

  hipMemsetAsync(d_ws, 0, 6400, stream);  // loss, hist, flag counts

  cc_np_k<<<(NSTAGE * KCODES + 255) / 256, 256, 0, stream>>>(cb0, cb1, cb2, cc);

  for (int s = 0; s < NSTAGE; ++s) {
    fast_k<<<NROWS / BM, NTH, 0, stream>>>(
        data, cbs[s], cb0, cb1, idx0, idx1, cc + s * KCODES, s, idxs[s],
        flagcnt + s, flagrows + s * MAXFLAG);
    refine_k<<<128, 256, 0, stream>>>(
        data, cbs[s], cb0, cb1, idx0, idx1, cc + s * KCODES, s,
        flagcnt + s, flagrows + s * MAXFLAG, idxs[s]);
  }

  final_k<<<NROWS / 4, 256, 0, stream>>>(
      data, cb0, cb1, cb2, idx0, idx1, idx2, quant, enc0, enc1, enc2,
      loss_sum, hist);

  finalize_k<<<1, 64, 0, stream>>>(hist, loss_sum, out_scalars);
}

// Round 13
// 1122.132 us; speedup vs baseline: 1.6236x; 1.6236x over previous
//
#include <hip/hip_runtime.h>
#include <math.h>

#define NROWS  65536
#define DDIM   256
#define KCODES 512
#define BM     32
#define BD     16
#define NTH    512
#define NSTAGE 3
#define MARGIN  1.0e-2f
#define MAXFLAG 8192
#define NLOSS   256   // loss accumulator slots (contention spreading)

// ---- np.sum(x*x,-1) model: numpy dispatched pairwise_sum, AVX512F width-16 ----
// (verified PASS in round 12 — do not touch)
__device__ __forceinline__ float np_sumsq256(const float* p) {
#pragma clang fp contract(off)
  float blk[2];
#pragma unroll
  for (int b = 0; b < 2; ++b) {
    const float* a = p + b * 128;
    float v[16];
#pragma unroll
    for (int l = 0; l < 16; ++l) {
      float p0a = a[l] * a[l];
      float p0b = a[64 + l] * a[64 + l];
      float P0 = p0a + p0b;
      float p1a = a[16 + l] * a[16 + l];
      float p1b = a[80 + l] * a[80 + l];
      float P1 = p1a + p1b;
      float p2a = a[32 + l] * a[32 + l];
      float p2b = a[96 + l] * a[96 + l];
      float P2 = p2a + p2b;
      float p3a = a[48 + l] * a[48 + l];
      float p3b = a[112 + l] * a[112 + l];
      float P3 = p3a + p3b;
      v[l] = (P0 + P1) + (P2 + P3);
    }
    float s1[8];
#pragma unroll
    for (int l = 0; l < 8; ++l) s1[l] = v[l] + v[l + 8];
    float s2[4];
#pragma unroll
    for (int l = 0; l < 4; ++l) s2[l] = s1[l] + s1[l + 4];
    float s3_0 = s2[0] + s2[2];
    float s3_1 = s2[1] + s2[3];
    blk[b] = s3_0 + s3_1;
  }
  return blk[0] + blk[1];
}

// ---- np c_einsum dot model: einsum_sumprod.c.src, npyv baseline SSE3 ----
// (verified PASS in round 12 — do not touch)
__device__ __forceinline__ float np_einsum_dot256(const float* __restrict__ x,
                                                  const float* __restrict__ c) {
#pragma clang fp contract(off)
  float v[4] = {0.f, 0.f, 0.f, 0.f};
  for (int t = 0; t < 16; ++t) {
    const float* a = x + t * 16;
    const float* b = c + t * 16;
#pragma unroll
    for (int l = 0; l < 4; ++l) {
      float ab3 = a[12 + l] * b[12 + l] + v[l];
      float ab2 = a[8 + l] * b[8 + l] + ab3;
      float ab1 = a[4 + l] * b[4 + l] + ab2;
      v[l] = a[0 + l] * b[0 + l] + ab1;
    }
  }
  return (v[0] + v[1]) + (v[2] + v[3]);
}

// ---------------- codebook norms, np-bitwise ----------------
__global__ void cc_np_k(const float* __restrict__ c0, const float* __restrict__ c1,
                        const float* __restrict__ c2, float* __restrict__ cc) {
  int t = blockIdx.x * blockDim.x + threadIdx.x;
  if (t >= NSTAGE * KCODES) return;
  const float* cb = (t < KCODES) ? c0 : (t < 2 * KCODES ? c1 : c2);
  cc[t] = np_sumsq256(cb + (size_t)(t & (KCODES - 1)) * DDIM);
}

// ---------------- fast distance + top-2 + flag ----------------
__global__ __launch_bounds__(NTH) void fast_k(
    const float* __restrict__ data, const float* __restrict__ cb,
    const float* __restrict__ cbA, const float* __restrict__ cbB,
    const int* __restrict__ idxA, const int* __restrict__ idxB,
    const float* __restrict__ ccs, int stage,
    int* __restrict__ idx_out, unsigned int* __restrict__ flagcnt,
    int* __restrict__ flagrows) {
  __shared__ float cbl[BD][KCODES];
  __shared__ float rl[BD][BM];
  __shared__ float ccl[KCODES];

  const int tid = threadIdx.x;
  const int lane = tid & 63;
  const int w = tid >> 6;
  const int rowbase = blockIdx.x * BM;

  ccl[tid] = ccs[tid];

  float acc[4][8];
#pragma unroll
  for (int m = 0; m < 4; ++m)
#pragma unroll
    for (int q = 0; q < 8; ++q) acc[m][q] = 0.0f;

  for (int c = 0; c < DDIM / BD; ++c) {
    const int d0 = c * BD;
    __syncthreads();
    {
      const float4* src = (const float4*)(cb + (size_t)tid * DDIM + d0);
#pragma unroll
      for (int j = 0; j < 4; ++j) {
        float4 v = src[j];
        cbl[4 * j + 0][tid] = v.x;
        cbl[4 * j + 1][tid] = v.y;
        cbl[4 * j + 2][tid] = v.z;
        cbl[4 * j + 3][tid] = v.w;
      }
    }
    if (tid < BM * 4) {
#pragma clang fp contract(off)
      const int rrow = tid >> 2;
      const int dsub = (tid & 3) * 4;
      const int r = rowbase + rrow;
      const size_t base = (size_t)r * DDIM + d0 + dsub;
      float4 dv = *(const float4*)(data + base);
      float x1[4] = {dv.x, dv.y, dv.z, dv.w};
      float res[4];
      if (stage == 0) {
#pragma unroll
        for (int j = 0; j < 4; ++j) res[j] = x1[j];
      } else {
        const int iA = idxA[r];
        float4 av = *(const float4*)(cbA + (size_t)iA * DDIM + d0 + dsub);
        float af[4] = {av.x, av.y, av.z, av.w};
        float a[4];
#pragma unroll
        for (int j = 0; j < 4; ++j) a[j] = x1[j] + (af[j] - x1[j]);
        if (stage == 2) {
          const int iB = idxB[r];
          float4 bv = *(const float4*)(cbB + (size_t)iB * DDIM + d0 + dsub);
          float bf[4] = {bv.x, bv.y, bv.z, bv.w};
#pragma unroll
          for (int j = 0; j < 4; ++j) {
            float x2 = x1[j] - a[j];
            float qst2 = x2 + (bf[j] - x2);
            a[j] = a[j] + qst2;
          }
        }
#pragma unroll
        for (int j = 0; j < 4; ++j) res[j] = x1[j] - a[j];
      }
      rl[dsub + 0][rrow] = res[0];
      rl[dsub + 1][rrow] = res[1];
      rl[dsub + 2][rrow] = res[2];
      rl[dsub + 3][rrow] = res[3];
    }
    __syncthreads();
#pragma unroll
    for (int dd = 0; dd < BD; ++dd) {
      float4 rv4 = *(const float4*)&rl[dd][w * 4];
      float4 ca = *(const float4*)&cbl[dd][lane * 4];
      float4 cbb = *(const float4*)&cbl[dd][256 + lane * 4];
      float rv[4] = {rv4.x, rv4.y, rv4.z, rv4.w};
      float cv[8] = {ca.x, ca.y, ca.z, ca.w, cbb.x, cbb.y, cbb.z, cbb.w};
#pragma unroll
      for (int m = 0; m < 4; ++m)
#pragma unroll
        for (int q = 0; q < 8; ++q)
          acc[m][q] = fmaf(rv[m], cv[q], acc[m][q]);
    }
  }

#pragma unroll
  for (int m = 0; m < 4; ++m) {
    float v1 = 3.0e38f, v2 = 3.0e38f;
    int i1 = 0x7fffffff;
#pragma unroll
    for (int q = 0; q < 8; ++q) {
      int k = (q < 4) ? (lane * 4 + q) : (256 + lane * 4 + (q - 4));
      float d = __fsub_rn(ccl[k], 2.0f * acc[m][q]);
      if (d < v1 || (d == v1 && k < i1)) { v2 = v1; v1 = d; i1 = k; }
      else if (d < v2) v2 = d;
    }
#pragma unroll
    for (int off = 1; off < 64; off <<= 1) {
      float ov1 = __shfl_xor(v1, off, 64);
      int oi1 = __shfl_xor(i1, off, 64);
      float ov2 = __shfl_xor(v2, off, 64);
      float worst = fmaxf(v1, ov1);
      v2 = fminf(fminf(v2, ov2), worst);
      if (ov1 < v1 || (ov1 == v1 && oi1 < i1)) { v1 = ov1; i1 = oi1; }
    }
    if (lane == 0) {
      int row = rowbase + w * 4 + m;
      idx_out[row] = i1;
      if (v2 - v1 < MARGIN) {
        unsigned pos = atomicAdd(flagcnt, 1u);
        if (pos < MAXFLAG) flagrows[pos] = row;
      }
    }
  }
}

// ---------------- np-bitwise refine for flagged rows ----------------
__global__ __launch_bounds__(256) void refine_k(
    const float* __restrict__ data, const float* __restrict__ cb,
    const float* __restrict__ cbA, const float* __restrict__ cbB,
    const int* __restrict__ idxA, const int* __restrict__ idxB,
    const float* __restrict__ ccs, int stage,
    const unsigned int* __restrict__ flagcnt, const int* __restrict__ flagrows,
    int* __restrict__ idx_out) {
  __shared__ float rl[DDIM];
  __shared__ float xxs;
  __shared__ float red_v[256];
  __shared__ int red_i[256];

  unsigned int n = *flagcnt;
  if (n > MAXFLAG) n = MAXFLAG;
  const int tid = threadIdx.x;

  for (unsigned f = blockIdx.x; f < n; f += gridDim.x) {
    const int r = flagrows[f];
    if (tid < 64) {
#pragma clang fp contract(off)
      const size_t base = (size_t)r * DDIM + tid * 4;
      float4 dv = *(const float4*)(data + base);
      float x1[4] = {dv.x, dv.y, dv.z, dv.w};
      float res[4];
      if (stage == 0) {
#pragma unroll
        for (int j = 0; j < 4; ++j) res[j] = x1[j];
      } else {
        const int iA = idxA[r];
        float4 av = *(const float4*)(cbA + (size_t)iA * DDIM + tid * 4);
        float af[4] = {av.x, av.y, av.z, av.w};
        float a[4];
#pragma unroll
        for (int j = 0; j < 4; ++j) a[j] = x1[j] + (af[j] - x1[j]);
        if (stage == 2) {
          const int iB = idxB[r];
          float4 bv = *(const float4*)(cbB + (size_t)iB * DDIM + tid * 4);
          float bf[4] = {bv.x, bv.y, bv.z, bv.w};
#pragma unroll
          for (int j = 0; j < 4; ++j) {
            float x2 = x1[j] - a[j];
            float qst2 = x2 + (bf[j] - x2);
            a[j] = a[j] + qst2;
          }
        }
#pragma unroll
        for (int j = 0; j < 4; ++j) res[j] = x1[j] - a[j];
      }
#pragma unroll
      for (int j = 0; j < 4; ++j) rl[tid * 4 + j] = res[j];
    }
    __syncthreads();
    if (tid == 0) xxs = np_sumsq256(rl);
    __syncthreads();

    float bv = 3.0e38f;
    int bi = 0x7fffffff;
#pragma unroll
    for (int h = 0; h < 2; ++h) {
      const int k = tid + h * 256;
      float d;
      {
#pragma clang fp contract(off)
        float dot = np_einsum_dot256(rl, cb + (size_t)k * DDIM);
        float t1 = xxs - 2.0f * dot;
        d = t1 + ccs[k];
      }
      if (d < bv || (d == bv && k < bi)) { bv = d; bi = k; }
    }
    red_v[tid] = bv;
    red_i[tid] = bi;
    __syncthreads();
    for (int sgap = 128; sgap > 0; sgap >>= 1) {
      if (tid < sgap) {
        float o = red_v[tid + sgap];
        int oi = red_i[tid + sgap];
        if (o < red_v[tid] || (o == red_v[tid] && oi < red_i[tid])) {
          red_v[tid] = o;
          red_i[tid] = oi;
        }
      }
      __syncthreads();
    }
    if (tid == 0) idx_out[r] = red_i[0];
    __syncthreads();
  }
}

// ---------------- final pass: quantized, one-hots (incl zeros), hist, loss ----
// Loss: per-wave shuffle reduce -> LDS -> ONE atomic per block into 256 slots
// (blockIdx & 255) — kills the single-address f64 atomic serialization that
// made this kernel 801us (675 GB/s, VALUBusy 2.6%).
__global__ __launch_bounds__(256) void final_k(
    const float* __restrict__ data, const float* __restrict__ cb0,
    const float* __restrict__ cb1, const float* __restrict__ cb2,
    const int* __restrict__ idx0, const int* __restrict__ idx1,
    const int* __restrict__ idx2, float* __restrict__ quant,
    float* __restrict__ enc0, float* __restrict__ enc1,
    float* __restrict__ enc2, double* __restrict__ loss_slots,
    unsigned int* __restrict__ hist) {
  __shared__ double wsum[4];
  const int lane = threadIdx.x & 63;
  const int w = threadIdx.x >> 6;
  const int r = blockIdx.x * 4 + w;
  const int i0 = idx0[r], i1 = idx1[r], i2 = idx2[r];
  const size_t base = (size_t)r * DDIM + lane * 4;
  float4 dv = *(const float4*)(data + base);
  float4 c0v = *(const float4*)(cb0 + (size_t)i0 * DDIM + lane * 4);
  float4 c1v = *(const float4*)(cb1 + (size_t)i1 * DDIM + lane * 4);
  float4 c2v = *(const float4*)(cb2 + (size_t)i2 * DDIM + lane * 4);
  float df[4] = {dv.x, dv.y, dv.z, dv.w};
  float q0f[4] = {c0v.x, c0v.y, c0v.z, c0v.w};
  float q1f[4] = {c1v.x, c1v.y, c1v.z, c1v.w};
  float q2f[4] = {c2v.x, c2v.y, c2v.z, c2v.w};
  float qout[4];
  double lsum = 0.0;
  {
#pragma clang fp contract(off)
#pragma unroll
    for (int j = 0; j < 4; ++j) {
      float x1 = df[j];
      float d1 = q0f[j] - x1;
      float qst1 = x1 + d1;
      float a1 = qst1;
      float x2 = x1 - a1;
      float d2 = q1f[j] - x2;
      float qst2 = x2 + d2;
      float a2 = a1 + qst2;
      float x3 = x1 - a2;
      float d3 = q2f[j] - x3;
      float qst3 = x3 + d3;
      float a3 = a2 + qst3;
      qout[j] = a3;
      lsum += (double)d1 * d1 + (double)d2 * d2 + (double)d3 * d3;
    }
  }
  float4 qv = {qout[0], qout[1], qout[2], qout[3]};
  *(float4*)(quant + base) = qv;

  // one-hot rows (zeros + single 1), 8 cols per lane per enc
  const int kb = lane * 8;
  float* eptr[3] = {enc0, enc1, enc2};
  int eidx[3] = {i0, i1, i2};
#pragma unroll
  for (int e = 0; e < 3; ++e) {
    float4 u0, u1;
    u0.x = (kb + 0 == eidx[e]) ? 1.0f : 0.0f;
    u0.y = (kb + 1 == eidx[e]) ? 1.0f : 0.0f;
    u0.z = (kb + 2 == eidx[e]) ? 1.0f : 0.0f;
    u0.w = (kb + 3 == eidx[e]) ? 1.0f : 0.0f;
    u1.x = (kb + 4 == eidx[e]) ? 1.0f : 0.0f;
    u1.y = (kb + 5 == eidx[e]) ? 1.0f : 0.0f;
    u1.z = (kb + 6 == eidx[e]) ? 1.0f : 0.0f;
    u1.w = (kb + 7 == eidx[e]) ? 1.0f : 0.0f;
    float* dst = eptr[e] + (size_t)r * KCODES + kb;
    *(float4*)(dst) = u0;
    *(float4*)(dst + 4) = u1;
  }

#pragma unroll
  for (int off = 1; off < 64; off <<= 1) lsum += __shfl_xor(lsum, off, 64);
  if (lane == 0) {
    wsum[w] = lsum;
    atomicAdd(&hist[i0], 1u);
  } else if (lane == 1) {
    atomicAdd(&hist[KCODES + i1], 1u);
  } else if (lane == 2) {
    atomicAdd(&hist[2 * KCODES + i2], 1u);
  }
  __syncthreads();
  if (threadIdx.x == 0) {
    double bsum = (wsum[0] + wsum[1]) + (wsum[2] + wsum[3]);
    atomicAdd(&loss_slots[blockIdx.x & (NLOSS - 1)], bsum);
  }
}

// ---------------- scalars ----------------
__global__ void finalize_k(const unsigned int* __restrict__ hist,
                           const double* __restrict__ loss_slots,
                           float* __restrict__ out_scalars) {
  int lane = threadIdx.x;  // 64 threads
  double te = 0.0;
  for (int s = 0; s < NSTAGE; ++s) {
    double e = 0.0;
    for (int j = 0; j < KCODES / 64; ++j) {
      int k = j * 64 + lane;
      float pf = (float)hist[s * KCODES + k] * (1.0f / 65536.0f);  // exact
      float sf = __fadd_rn(pf, 1e-10f);
      e += (double)pf * log((double)sf);
    }
#pragma unroll
    for (int off = 1; off < 64; off <<= 1) e += __shfl_xor(e, off, 64);
    te += -e;
  }
  // sum the 256 loss slots (4 per lane)
  double ls = loss_slots[lane] + loss_slots[64 + lane] +
              loss_slots[128 + lane] + loss_slots[192 + lane];
#pragma unroll
  for (int off = 1; off < 64; off <<= 1) ls += __shfl_xor(ls, off, 64);
  if (lane == 0) {
    double tl = 1.25 * ls * (1.0 / 16777216.0);  // (q+0.25e)/(N*D)
    out_scalars[0] = (float)tl;
    out_scalars[1] = (float)te;
  }
}

extern "C" void kernel_launch(void* const* d_in, const int* in_sizes, int n_in,
                              void* d_out, int out_size, void* d_ws, size_t ws_size,
                              hipStream_t stream) {
  const float* data = (const float*)d_in[0];
  const float* cb0 = (const float*)d_in[1];
  const float* cb1 = (const float*)d_in[2];
  const float* cb2 = (const float*)d_in[3];
  const float* cbs[3] = {cb0, cb1, cb2};
  float* out = (float*)d_out;
  float* quant = out;
  float* enc0 = out + (size_t)NROWS * DDIM;
  float* enc1 = enc0 + (size_t)NROWS * KCODES;
  float* enc2 = enc1 + (size_t)NROWS * KCODES;
  float* out_scalars = enc2 + (size_t)NROWS * KCODES;

  // ws: [0) loss_slots f64 x256 (2048) | 2048) hist u32x1536 | 8192) flagcnt u32x3 |
  //     8320) flagrows i32[3][MAXFLAG] | 106688) cc f32x1536 | 112832) idx i32[3][N]
  double* loss_slots = (double*)d_ws;
  unsigned int* hist = (unsigned int*)((char*)d_ws + 2048);
  unsigned int* flagcnt = (unsigned int*)((char*)d_ws + 8192);
  int* flagrows = (int*)((char*)d_ws + 8320);
  float* cc = (float*)((char*)d_ws + 106688);
  int* idx0 = (int*)((char*)d_ws + 112832);
  int* idx1 = idx0 + NROWS;
  int* idx2 = idx1 + NROWS;
  int* idxs[3] = {idx0, idx1, idx2};

  hipMemsetAsync(d_ws, 0, 8320, stream);  // loss slots, hist, flag counts

  cc_np_k<<<(NSTAGE * KCODES + 255) / 256, 256, 0, stream>>>(cb0, cb1, cb2, cc);

  for (int s = 0; s < NSTAGE; ++s) {
    fast_k<<<NROWS / BM, NTH, 0, stream>>>(
        data, cbs[s], cb0, cb1, idx0, idx1, cc + s * KCODES, s, idxs[s],
        flagcnt + s, flagrows + s * MAXFLAG);
    refine_k<<<128, 256, 0, stream>>>(
        data, cbs[s], cb0, cb1, idx0, idx1, cc + s * KCODES, s,
        flagcnt + s, flagrows + s * MAXFLAG, idxs[s]);
  }

  final_k<<<NROWS / 4, 256, 0, stream>>>(
      data, cb0, cb1, cb2, idx0, idx1, idx2, quant, enc0, enc1, enc2,
      loss_slots, hist);

  finalize_k<<<1, 64, 0, stream>>>(hist, loss_slots, out_scalars);
}

// Round 14
// 1068.225 us; speedup vs baseline: 1.7055x; 1.0505x over previous
//
#include <hip/hip_runtime.h>
#include <math.h>

#define NROWS  65536
#define DDIM   256
#define KCODES 512
#define NTH    512
#define NSTAGE 3
#define MARGIN  2.5e-2f
#define MAXFLAG 8192
#define NLOSS   256
#define MB      64    // rows per block in mfma kernel
#define BK      32    // k per chunk = one mfma K

typedef __attribute__((ext_vector_type(8))) short short8v;
typedef __attribute__((ext_vector_type(4))) float f32x4;

__device__ __forceinline__ unsigned short f2bf(float x) {
  unsigned int u = __float_as_uint(x);
  unsigned int r = (u + 0x7fffu + ((u >> 16) & 1u)) >> 16;
  return (unsigned short)r;
}
__device__ __forceinline__ float bf2f(unsigned short h) {
  return __uint_as_float(((unsigned int)h) << 16);
}

// ---- np.sum(x*x,-1) model: dispatched pairwise_sum, AVX512F (r12 PASS — do not touch)
__device__ __forceinline__ float np_sumsq256(const float* p) {
#pragma clang fp contract(off)
  float blk[2];
#pragma unroll
  for (int b = 0; b < 2; ++b) {
    const float* a = p + b * 128;
    float v[16];
#pragma unroll
    for (int l = 0; l < 16; ++l) {
      float p0a = a[l] * a[l];
      float p0b = a[64 + l] * a[64 + l];
      float P0 = p0a + p0b;
      float p1a = a[16 + l] * a[16 + l];
      float p1b = a[80 + l] * a[80 + l];
      float P1 = p1a + p1b;
      float p2a = a[32 + l] * a[32 + l];
      float p2b = a[96 + l] * a[96 + l];
      float P2 = p2a + p2b;
      float p3a = a[48 + l] * a[48 + l];
      float p3b = a[112 + l] * a[112 + l];
      float P3 = p3a + p3b;
      v[l] = (P0 + P1) + (P2 + P3);
    }
    float s1[8];
#pragma unroll
    for (int l = 0; l < 8; ++l) s1[l] = v[l] + v[l + 8];
    float s2[4];
#pragma unroll
    for (int l = 0; l < 4; ++l) s2[l] = s1[l] + s1[l + 4];
    float s3_0 = s2[0] + s2[2];
    float s3_1 = s2[1] + s2[3];
    blk[b] = s3_0 + s3_1;
  }
  return blk[0] + blk[1];
}

// ---- np c_einsum dot model: baseline SSE3 (r12 PASS — do not touch)
__device__ __forceinline__ float np_einsum_dot256(const float* __restrict__ x,
                                                  const float* __restrict__ c) {
#pragma clang fp contract(off)
  float v[4] = {0.f, 0.f, 0.f, 0.f};
  for (int t = 0; t < 16; ++t) {
    const float* a = x + t * 16;
    const float* b = c + t * 16;
#pragma unroll
    for (int l = 0; l < 4; ++l) {
      float ab3 = a[12 + l] * b[12 + l] + v[l];
      float ab2 = a[8 + l] * b[8 + l] + ab3;
      float ab1 = a[4 + l] * b[4 + l] + ab2;
      v[l] = a[0 + l] * b[0 + l] + ab1;
    }
  }
  return (v[0] + v[1]) + (v[2] + v[3]);
}

// ---------------- codebook norms, np-bitwise ----------------
__global__ void cc_np_k(const float* __restrict__ c0, const float* __restrict__ c1,
                        const float* __restrict__ c2, float* __restrict__ cc) {
  int t = blockIdx.x * blockDim.x + threadIdx.x;
  if (t >= NSTAGE * KCODES) return;
  const float* cb = (t < KCODES) ? c0 : (t < 2 * KCODES ? c1 : c2);
  cc[t] = np_sumsq256(cb + (size_t)(t & (KCODES - 1)) * DDIM);
}

// ---------------- split codebooks into bf16 hi/lo ----------------
__global__ void split_cb_k(const float* __restrict__ c0, const float* __restrict__ c1,
                           const float* __restrict__ c2,
                           unsigned short* __restrict__ Ch,
                           unsigned short* __restrict__ Cl) {
  int t = blockIdx.x * 256 + threadIdx.x;
  if (t >= NSTAGE * KCODES * 32) return;
  int s = t / (KCODES * 32);
  int rem = t - s * KCODES * 32;
  int code = rem >> 5;
  int gran = rem & 31;
  const float* cb = (s == 0) ? c0 : (s == 1 ? c1 : c2);
  const float* src = cb + (size_t)code * DDIM + gran * 8;
  unsigned short* dh = Ch + ((size_t)s * KCODES + code) * DDIM + gran * 8;
  unsigned short* dl = Cl + ((size_t)s * KCODES + code) * DDIM + gran * 8;
#pragma unroll
  for (int j = 0; j < 8; ++j) {
    float x = src[j];
    unsigned short h = f2bf(x);
    dh[j] = h;
    dl[j] = f2bf(x - bf2f(h));
  }
}

// ---------------- MFMA fast path: distances + top-2 + flag ----------------
// Block: 512 thr = 8 waves; 64 rows x all 512 codes; BK=32 per chunk.
// 3-pass bf16 split GEMM: acc += Ah*Bh + Ah*Bl + Al*Bh (same f32 acc).
// LDS: A_h[64][32] | A_l | B_h[512][32] | B_l | cc[512], 16B-granule XOR swizzle.
#define A_H_OFF 0
#define A_L_OFF 4096
#define B_H_OFF 8192
#define B_L_OFF 40960
#define CC_OFF  73728
#define SMEM_SZ 75776

__global__ __launch_bounds__(NTH) void mfma_fast_k(
    const float* __restrict__ data,
    const unsigned short* __restrict__ Ch, const unsigned short* __restrict__ Cl,
    const float* __restrict__ cbA, const float* __restrict__ cbB,
    const int* __restrict__ idxA, const int* __restrict__ idxB,
    const float* __restrict__ ccs, int stage,
    int* __restrict__ idx_out, unsigned int* __restrict__ flagcnt,
    int* __restrict__ flagrows) {
  __shared__ char smem[SMEM_SZ];

  const int tid = threadIdx.x;
  const int lane = tid & 63;
  const int w = tid >> 6;
  const int rowbase = blockIdx.x * MB;

  *(float*)(smem + CC_OFF + tid * 4) = ccs[tid];

  f32x4 acc[4][4];
#pragma unroll
  for (int rt = 0; rt < 4; ++rt)
#pragma unroll
    for (int ct = 0; ct < 4; ++ct) {
      acc[rt][ct].x = 0.f; acc[rt][ct].y = 0.f;
      acc[rt][ct].z = 0.f; acc[rt][ct].w = 0.f;
    }

  for (int chunk = 0; chunk < DDIM / BK; ++chunk) {
    const int k0 = chunk * BK;
    __syncthreads();
    if (tid < 256) {
      // ---- A staging: residual chain f32 (verified op order) -> bf16 h/l
      const int lr = tid >> 2;
      const int gran = tid & 3;
      const int r = rowbase + lr;
      const int d0 = k0 + gran * 8;
      float res[8];
      int iA = 0, iB = 0;
      if (stage >= 1) iA = idxA[r];
      if (stage == 2) iB = idxB[r];
      {
#pragma clang fp contract(off)
#pragma unroll
        for (int half = 0; half < 2; ++half) {
          const size_t base = (size_t)r * DDIM + d0 + half * 4;
          float4 dv = *(const float4*)(data + base);
          float x1[4] = {dv.x, dv.y, dv.z, dv.w};
          float rr[4];
          if (stage == 0) {
#pragma unroll
            for (int j = 0; j < 4; ++j) rr[j] = x1[j];
          } else {
            float4 av = *(const float4*)(cbA + (size_t)iA * DDIM + d0 + half * 4);
            float af[4] = {av.x, av.y, av.z, av.w};
            float a[4];
#pragma unroll
            for (int j = 0; j < 4; ++j) a[j] = x1[j] + (af[j] - x1[j]);
            if (stage == 2) {
              float4 bv = *(const float4*)(cbB + (size_t)iB * DDIM + d0 + half * 4);
              float bf[4] = {bv.x, bv.y, bv.z, bv.w};
#pragma unroll
              for (int j = 0; j < 4; ++j) {
                float x2 = x1[j] - a[j];
                float qst2 = x2 + (bf[j] - x2);
                a[j] = a[j] + qst2;
              }
            }
#pragma unroll
            for (int j = 0; j < 4; ++j) rr[j] = x1[j] - a[j];
          }
#pragma unroll
          for (int j = 0; j < 4; ++j) res[half * 4 + j] = rr[j];
        }
      }
      unsigned int hw[4], lw[4];
#pragma unroll
      for (int j = 0; j < 4; ++j) {
        unsigned short h0 = f2bf(res[2 * j]);
        unsigned short h1 = f2bf(res[2 * j + 1]);
        unsigned short l0 = f2bf(res[2 * j] - bf2f(h0));
        unsigned short l1 = f2bf(res[2 * j + 1] - bf2f(h1));
        hw[j] = (unsigned int)h0 | ((unsigned int)h1 << 16);
        lw[j] = (unsigned int)l0 | ((unsigned int)l1 << 16);
      }
      const int byte = (lr * 64 + gran * 16) ^ ((lr & 7) << 4);
      *(uint4*)(smem + A_H_OFF + byte) = make_uint4(hw[0], hw[1], hw[2], hw[3]);
      *(uint4*)(smem + A_L_OFF + byte) = make_uint4(lw[0], lw[1], lw[2], lw[3]);
    } else {
      // ---- B staging: pre-split codebook bf16 h/l from ws
      const int u = tid - 256;
#pragma unroll
      for (int cc2 = 0; cc2 < 2; ++cc2) {
        const int code = u * 2 + cc2;
        const uint4* srcH = (const uint4*)(Ch + (size_t)code * DDIM + k0);
        const uint4* srcL = (const uint4*)(Cl + (size_t)code * DDIM + k0);
#pragma unroll
        for (int g = 0; g < 4; ++g) {
          const int byte = (code * 64 + g * 16) ^ ((code & 7) << 4);
          *(uint4*)(smem + B_H_OFF + byte) = srcH[g];
          *(uint4*)(smem + B_L_OFF + byte) = srcL[g];
        }
      }
    }
    __syncthreads();

    const int g = lane >> 4, c16 = lane & 15;
    short8v ah[4], al[4];
#pragma unroll
    for (int rt = 0; rt < 4; ++rt) {
      const int row = rt * 16 + c16;
      const int byte = (row * 64 + g * 16) ^ ((row & 7) << 4);
      ah[rt] = *(short8v*)(smem + A_H_OFF + byte);
      al[rt] = *(short8v*)(smem + A_L_OFF + byte);
    }
#pragma unroll
    for (int ct = 0; ct < 4; ++ct) {
      const int code = w * 64 + ct * 16 + c16;
      const int byte = (code * 64 + g * 16) ^ ((code & 7) << 4);
      short8v bh = *(short8v*)(smem + B_H_OFF + byte);
      short8v bl = *(short8v*)(smem + B_L_OFF + byte);
#pragma unroll
      for (int rt = 0; rt < 4; ++rt) {
        acc[rt][ct] = __builtin_amdgcn_mfma_f32_16x16x32_bf16(ah[rt], bh, acc[rt][ct], 0, 0, 0);
        acc[rt][ct] = __builtin_amdgcn_mfma_f32_16x16x32_bf16(ah[rt], bl, acc[rt][ct], 0, 0, 0);
        acc[rt][ct] = __builtin_amdgcn_mfma_f32_16x16x32_bf16(al[rt], bh, acc[rt][ct], 0, 0, 0);
      }
    }
  }
  __syncthreads();

  // ---- epilogue: d = cc - 2*dot, top-2 per row -> idx + flag
  float* red = (float*)(smem + B_H_OFF);  // [64 rows][8 waves][4 f32]
  const float* ccl = (const float*)(smem + CC_OFF);
  const int g = lane >> 4, c16 = lane & 15;
#pragma unroll
  for (int rt = 0; rt < 4; ++rt) {
#pragma unroll
    for (int reg = 0; reg < 4; ++reg) {
      const int row = rt * 16 + g * 4 + reg;
      float v1 = 3.0e38f, v2 = 3.0e38f;
      int i1 = 0x7fffffff;
#pragma unroll
      for (int ct = 0; ct < 4; ++ct) {
        const int col = w * 64 + ct * 16 + c16;
        float dd = ccl[col] - 2.0f * acc[rt][ct][reg];
        if (dd < v1 || (dd == v1 && col < i1)) { v2 = v1; v1 = dd; i1 = col; }
        else if (dd < v2) v2 = dd;
      }
#pragma unroll
      for (int m = 1; m < 16; m <<= 1) {
        float ov1 = __shfl_xor(v1, m, 64);
        int oi1 = __shfl_xor(i1, m, 64);
        float ov2 = __shfl_xor(v2, m, 64);
        float worst = fmaxf(v1, ov1);
        v2 = fminf(fminf(v2, ov2), worst);
        if (ov1 < v1 || (ov1 == v1 && oi1 < i1)) { v1 = ov1; i1 = oi1; }
      }
      if (c16 == 0) {
        float* slot = red + (size_t)(row * 8 + w) * 4;
        slot[0] = v1;
        ((int*)slot)[1] = i1;
        slot[2] = v2;
      }
    }
  }
  __syncthreads();
  if (tid < MB) {
    float v1 = 3.0e38f, v2 = 3.0e38f;
    int i1 = 0x7fffffff;
#pragma unroll
    for (int ww = 0; ww < 8; ++ww) {
      const float* slot = red + (size_t)(tid * 8 + ww) * 4;
      float ov1 = slot[0];
      int oi1 = ((const int*)slot)[1];
      float ov2 = slot[2];
      float worst = fmaxf(v1, ov1);
      v2 = fminf(fminf(v2, ov2), worst);
      if (ov1 < v1 || (ov1 == v1 && oi1 < i1)) { v1 = ov1; i1 = oi1; }
    }
    const int r = rowbase + tid;
    idx_out[r] = i1;
    if (v2 - v1 < MARGIN) {
      unsigned pos = atomicAdd(flagcnt, 1u);
      if (pos < MAXFLAG) flagrows[pos] = r;
    }
  }
}

// ---------------- np-bitwise refine for flagged rows (r12 PASS) ----------------
__global__ __launch_bounds__(256) void refine_k(
    const float* __restrict__ data, const float* __restrict__ cb,
    const float* __restrict__ cbA, const float* __restrict__ cbB,
    const int* __restrict__ idxA, const int* __restrict__ idxB,
    const float* __restrict__ ccs, int stage,
    const unsigned int* __restrict__ flagcnt, const int* __restrict__ flagrows,
    int* __restrict__ idx_out) {
  __shared__ float rl[DDIM];
  __shared__ float xxs;
  __shared__ float red_v[256];
  __shared__ int red_i[256];

  unsigned int n = *flagcnt;
  if (n > MAXFLAG) n = MAXFLAG;
  const int tid = threadIdx.x;

  for (unsigned f = blockIdx.x; f < n; f += gridDim.x) {
    const int r = flagrows[f];
    if (tid < 64) {
#pragma clang fp contract(off)
      const size_t base = (size_t)r * DDIM + tid * 4;
      float4 dv = *(const float4*)(data + base);
      float x1[4] = {dv.x, dv.y, dv.z, dv.w};
      float res[4];
      if (stage == 0) {
#pragma unroll
        for (int j = 0; j < 4; ++j) res[j] = x1[j];
      } else {
        const int iA = idxA[r];
        float4 av = *(const float4*)(cbA + (size_t)iA * DDIM + tid * 4);
        float af[4] = {av.x, av.y, av.z, av.w};
        float a[4];
#pragma unroll
        for (int j = 0; j < 4; ++j) a[j] = x1[j] + (af[j] - x1[j]);
        if (stage == 2) {
          const int iB = idxB[r];
          float4 bv = *(const float4*)(cbB + (size_t)iB * DDIM + tid * 4);
          float bf[4] = {bv.x, bv.y, bv.z, bv.w};
#pragma unroll
          for (int j = 0; j < 4; ++j) {
            float x2 = x1[j] - a[j];
            float qst2 = x2 + (bf[j] - x2);
            a[j] = a[j] + qst2;
          }
        }
#pragma unroll
        for (int j = 0; j < 4; ++j) res[j] = x1[j] - a[j];
      }
#pragma unroll
      for (int j = 0; j < 4; ++j) rl[tid * 4 + j] = res[j];
    }
    __syncthreads();
    if (tid == 0) xxs = np_sumsq256(rl);
    __syncthreads();

    float bv = 3.0e38f;
    int bi = 0x7fffffff;
#pragma unroll
    for (int h = 0; h < 2; ++h) {
      const int k = tid + h * 256;
      float d;
      {
#pragma clang fp contract(off)
        float dot = np_einsum_dot256(rl, cb + (size_t)k * DDIM);
        float t1 = xxs - 2.0f * dot;
        d = t1 + ccs[k];
      }
      if (d < bv || (d == bv && k < bi)) { bv = d; bi = k; }
    }
    red_v[tid] = bv;
    red_i[tid] = bi;
    __syncthreads();
    for (int sgap = 128; sgap > 0; sgap >>= 1) {
      if (tid < sgap) {
        float o = red_v[tid + sgap];
        int oi = red_i[tid + sgap];
        if (o < red_v[tid] || (o == red_v[tid] && oi < red_i[tid])) {
          red_v[tid] = o;
          red_i[tid] = oi;
        }
      }
      __syncthreads();
    }
    if (tid == 0) idx_out[r] = red_i[0];
    __syncthreads();
  }
}

// ---------------- final pass (r13: spread loss atomics) ----------------
__global__ __launch_bounds__(256) void final_k(
    const float* __restrict__ data, const float* __restrict__ cb0,
    const float* __restrict__ cb1, const float* __restrict__ cb2,
    const int* __restrict__ idx0, const int* __restrict__ idx1,
    const int* __restrict__ idx2, float* __restrict__ quant,
    float* __restrict__ enc0, float* __restrict__ enc1,
    float* __restrict__ enc2, double* __restrict__ loss_slots,
    unsigned int* __restrict__ hist) {
  __shared__ double wsum[4];
  const int lane = threadIdx.x & 63;
  const int w = threadIdx.x >> 6;
  const int r = blockIdx.x * 4 + w;
  const int i0 = idx0[r], i1 = idx1[r], i2 = idx2[r];
  const size_t base = (size_t)r * DDIM + lane * 4;
  float4 dv = *(const float4*)(data + base);
  float4 c0v = *(const float4*)(cb0 + (size_t)i0 * DDIM + lane * 4);
  float4 c1v = *(const float4*)(cb1 + (size_t)i1 * DDIM + lane * 4);
  float4 c2v = *(const float4*)(cb2 + (size_t)i2 * DDIM + lane * 4);
  float df[4] = {dv.x, dv.y, dv.z, dv.w};
  float q0f[4] = {c0v.x, c0v.y, c0v.z, c0v.w};
  float q1f[4] = {c1v.x, c1v.y, c1v.z, c1v.w};
  float q2f[4] = {c2v.x, c2v.y, c2v.z, c2v.w};
  float qout[4];
  double lsum = 0.0;
  {
#pragma clang fp contract(off)
#pragma unroll
    for (int j = 0; j < 4; ++j) {
      float x1 = df[j];
      float d1 = q0f[j] - x1;
      float qst1 = x1 + d1;
      float a1 = qst1;
      float x2 = x1 - a1;
      float d2 = q1f[j] - x2;
      float qst2 = x2 + d2;
      float a2 = a1 + qst2;
      float x3 = x1 - a2;
      float d3 = q2f[j] - x3;
      float qst3 = x3 + d3;
      float a3 = a2 + qst3;
      qout[j] = a3;
      lsum += (double)d1 * d1 + (double)d2 * d2 + (double)d3 * d3;
    }
  }
  float4 qv = {qout[0], qout[1], qout[2], qout[3]};
  *(float4*)(quant + base) = qv;

  const int kb = lane * 8;
  float* eptr[3] = {enc0, enc1, enc2};
  int eidx[3] = {i0, i1, i2};
#pragma unroll
  for (int e = 0; e < 3; ++e) {
    float4 u0, u1;
    u0.x = (kb + 0 == eidx[e]) ? 1.0f : 0.0f;
    u0.y = (kb + 1 == eidx[e]) ? 1.0f : 0.0f;
    u0.z = (kb + 2 == eidx[e]) ? 1.0f : 0.0f;
    u0.w = (kb + 3 == eidx[e]) ? 1.0f : 0.0f;
    u1.x = (kb + 4 == eidx[e]) ? 1.0f : 0.0f;
    u1.y = (kb + 5 == eidx[e]) ? 1.0f : 0.0f;
    u1.z = (kb + 6 == eidx[e]) ? 1.0f : 0.0f;
    u1.w = (kb + 7 == eidx[e]) ? 1.0f : 0.0f;
    float* dst = eptr[e] + (size_t)r * KCODES + kb;
    *(float4*)(dst) = u0;
    *(float4*)(dst + 4) = u1;
  }

#pragma unroll
  for (int off = 1; off < 64; off <<= 1) lsum += __shfl_xor(lsum, off, 64);
  if (lane == 0) {
    wsum[w] = lsum;
    atomicAdd(&hist[i0], 1u);
  } else if (lane == 1) {
    atomicAdd(&hist[KCODES + i1], 1u);
  } else if (lane == 2) {
    atomicAdd(&hist[2 * KCODES + i2], 1u);
  }
  __syncthreads();
  if (threadIdx.x == 0) {
    double bsum = (wsum[0] + wsum[1]) + (wsum[2] + wsum[3]);
    atomicAdd(&loss_slots[blockIdx.x & (NLOSS - 1)], bsum);
  }
}

// ---------------- scalars ----------------
__global__ void finalize_k(const unsigned int* __restrict__ hist,
                           const double* __restrict__ loss_slots,
                           float* __restrict__ out_scalars) {
  int lane = threadIdx.x;  // 64 threads
  double te = 0.0;
  for (int s = 0; s < NSTAGE; ++s) {
    double e = 0.0;
    for (int j = 0; j < KCODES / 64; ++j) {
      int k = j * 64 + lane;
      float pf = (float)hist[s * KCODES + k] * (1.0f / 65536.0f);
      float sf = __fadd_rn(pf, 1e-10f);
      e += (double)pf * log((double)sf);
    }
#pragma unroll
    for (int off = 1; off < 64; off <<= 1) e += __shfl_xor(e, off, 64);
    te += -e;
  }
  double ls = loss_slots[lane] + loss_slots[64 + lane] +
              loss_slots[128 + lane] + loss_slots[192 + lane];
#pragma unroll
  for (int off = 1; off < 64; off <<= 1) ls += __shfl_xor(ls, off, 64);
  if (lane == 0) {
    double tl = 1.25 * ls * (1.0 / 16777216.0);
    out_scalars[0] = (float)tl;
    out_scalars[1] = (float)te;
  }
}

extern "C" void kernel_launch(void* const* d_in, const int* in_sizes, int n_in,
                              void* d_out, int out_size, void* d_ws, size_t ws_size,
                              hipStream_t stream) {
  const float* data = (const float*)d_in[0];
  const float* cb0 = (const float*)d_in[1];
  const float* cb1 = (const float*)d_in[2];
  const float* cb2 = (const float*)d_in[3];
  const float* cbs[3] = {cb0, cb1, cb2};
  float* out = (float*)d_out;
  float* quant = out;
  float* enc0 = out + (size_t)NROWS * DDIM;
  float* enc1 = enc0 + (size_t)NROWS * KCODES;
  float* enc2 = enc1 + (size_t)NROWS * KCODES;
  float* out_scalars = enc2 + (size_t)NROWS * KCODES;

  // ws: [0) loss_slots f64x256 | 2048) hist u32x1536 | 8192) flagcnt u32x3 |
  //     8320) flagrows i32[3][8192] | 106688) cc f32x1536 | 112832) idx i32[3][N]
  //     | 899264) Ch bf16[3][512][256] | 1685696) Cl bf16[3][512][256]
  double* loss_slots = (double*)d_ws;
  unsigned int* hist = (unsigned int*)((char*)d_ws + 2048);
  unsigned int* flagcnt = (unsigned int*)((char*)d_ws + 8192);
  int* flagrows = (int*)((char*)d_ws + 8320);
  float* cc = (float*)((char*)d_ws + 106688);
  int* idx0 = (int*)((char*)d_ws + 112832);
  int* idx1 = idx0 + NROWS;
  int* idx2 = idx1 + NROWS;
  int* idxs[3] = {idx0, idx1, idx2};
  unsigned short* Ch = (unsigned short*)((char*)d_ws + 899264);
  unsigned short* Cl = (unsigned short*)((char*)d_ws + 1685696);

  hipMemsetAsync(d_ws, 0, 8320, stream);

  cc_np_k<<<(NSTAGE * KCODES + 255) / 256, 256, 0, stream>>>(cb0, cb1, cb2, cc);
  split_cb_k<<<(NSTAGE * KCODES * 32 + 255) / 256, 256, 0, stream>>>(
      cb0, cb1, cb2, Ch, Cl);

  for (int s = 0; s < NSTAGE; ++s) {
    mfma_fast_k<<<NROWS / MB, NTH, 0, stream>>>(
        data, Ch + (size_t)s * KCODES * DDIM, Cl + (size_t)s * KCODES * DDIM,
        cb0, cb1, idx0, idx1, cc + s * KCODES, s, idxs[s],
        flagcnt + s, flagrows + s * MAXFLAG);
    refine_k<<<128, 256, 0, stream>>>(
        data, cbs[s], cb0, cb1, idx0, idx1, cc + s * KCODES, s,
        flagcnt + s, flagrows + s * MAXFLAG, idxs[s]);
  }

  final_k<<<NROWS / 4, 256, 0, stream>>>(
      data, cb0, cb1, cb2, idx0, idx1, idx2, quant, enc0, enc1, enc2,
      loss_slots, hist);

  finalize_k<<<1, 64, 0, stream>>>(hist, loss_slots, out_scalars);
}

// Round 15
// 796.852 us; speedup vs baseline: 2.2863x; 1.3406x over previous
//
#include <hip/hip_runtime.h>
#include <math.h>

#define NROWS  65536
#define DDIM   256
#define KCODES 512
#define NTH    512
#define NSTAGE 3
#define MARGIN  2.5e-2f
#define MAXFLAG 8192
#define NLOSS   256
#define MB      64

typedef __attribute__((ext_vector_type(8))) short short8v;
typedef __attribute__((ext_vector_type(4))) float f32x4;

__device__ __forceinline__ unsigned short f2bf(float x) {
  unsigned int u = __float_as_uint(x);
  unsigned int r = (u + 0x7fffu + ((u >> 16) & 1u)) >> 16;
  return (unsigned short)r;
}
__device__ __forceinline__ float bf2f(unsigned short h) {
  return __uint_as_float(((unsigned int)h) << 16);
}

__device__ __forceinline__ void glds16(const void* g, void* l) {
  __builtin_amdgcn_global_load_lds(
      (const __attribute__((address_space(1))) unsigned int*)g,
      (__attribute__((address_space(3))) unsigned int*)l, 16, 0, 0);
}

// ---- np.sum(x*x,-1) model: dispatched pairwise_sum, AVX512F (r12 PASS — do not touch)
__device__ __forceinline__ float np_sumsq256(const float* p) {
#pragma clang fp contract(off)
  float blk[2];
#pragma unroll
  for (int b = 0; b < 2; ++b) {
    const float* a = p + b * 128;
    float v[16];
#pragma unroll
    for (int l = 0; l < 16; ++l) {
      float p0a = a[l] * a[l];
      float p0b = a[64 + l] * a[64 + l];
      float P0 = p0a + p0b;
      float p1a = a[16 + l] * a[16 + l];
      float p1b = a[80 + l] * a[80 + l];
      float P1 = p1a + p1b;
      float p2a = a[32 + l] * a[32 + l];
      float p2b = a[96 + l] * a[96 + l];
      float P2 = p2a + p2b;
      float p3a = a[48 + l] * a[48 + l];
      float p3b = a[112 + l] * a[112 + l];
      float P3 = p3a + p3b;
      v[l] = (P0 + P1) + (P2 + P3);
    }
    float s1[8];
#pragma unroll
    for (int l = 0; l < 8; ++l) s1[l] = v[l] + v[l + 8];
    float s2[4];
#pragma unroll
    for (int l = 0; l < 4; ++l) s2[l] = s1[l] + s1[l + 4];
    float s3_0 = s2[0] + s2[2];
    float s3_1 = s2[1] + s2[3];
    blk[b] = s3_0 + s3_1;
  }
  return blk[0] + blk[1];
}

// ---- np c_einsum dot model: baseline SSE3 (r12 PASS — do not touch)
__device__ __forceinline__ float np_einsum_dot256(const float* __restrict__ x,
                                                  const float* __restrict__ c) {
#pragma clang fp contract(off)
  float v[4] = {0.f, 0.f, 0.f, 0.f};
  for (int t = 0; t < 16; ++t) {
    const float* a = x + t * 16;
    const float* b = c + t * 16;
#pragma unroll
    for (int l = 0; l < 4; ++l) {
      float ab3 = a[12 + l] * b[12 + l] + v[l];
      float ab2 = a[8 + l] * b[8 + l] + ab3;
      float ab1 = a[4 + l] * b[4 + l] + ab2;
      v[l] = a[0 + l] * b[0 + l] + ab1;
    }
  }
  return (v[0] + v[1]) + (v[2] + v[3]);
}

// ---------------- codebook norms, np-bitwise ----------------
__global__ void cc_np_k(const float* __restrict__ c0, const float* __restrict__ c1,
                        const float* __restrict__ c2, float* __restrict__ cc) {
  int t = blockIdx.x * blockDim.x + threadIdx.x;
  if (t >= NSTAGE * KCODES) return;
  const float* cb = (t < KCODES) ? c0 : (t < 2 * KCODES ? c1 : c2);
  cc[t] = np_sumsq256(cb + (size_t)(t & (KCODES - 1)) * DDIM);
}

// ---------------- split codebooks into bf16 hi/lo, PRE-SWIZZLED chunk-blocked ----
// Layout: [stage][chunk 0..7][32KB block]; granule (code, g16) at byte
// (code*64 + g16*16) ^ ((code&7)<<4) within the block. After linear
// global_load_lds staging, LDS holds the swizzled tile directly.
__global__ void split_cb_k(const float* __restrict__ c0, const float* __restrict__ c1,
                           const float* __restrict__ c2,
                           unsigned short* __restrict__ Ch,
                           unsigned short* __restrict__ Cl) {
  int t = blockIdx.x * 256 + threadIdx.x;
  if (t >= NSTAGE * KCODES * 32) return;
  int s = t / (KCODES * 32);
  int rem = t - s * KCODES * 32;
  int code = rem >> 5;
  int gran = rem & 31;          // 16B granule over K: k = gran*8
  int chunk = gran >> 2;
  int g16 = gran & 3;
  const float* cb = (s == 0) ? c0 : (s == 1 ? c1 : c2);
  const float* src = cb + (size_t)code * DDIM + gran * 8;
  unsigned short hv[8], lv[8];
#pragma unroll
  for (int j = 0; j < 8; ++j) {
    float x = src[j];
    unsigned short h = f2bf(x);
    hv[j] = h;
    lv[j] = f2bf(x - bf2f(h));
  }
  size_t off = (size_t)s * 262144 + chunk * 32768 +
               ((code * 64 + g16 * 16) ^ ((code & 7) << 4));
  *(uint4*)((char*)Ch + off) = *(uint4*)hv;
  *(uint4*)((char*)Cl + off) = *(uint4*)lv;
}

// ---------------- GEMM + top-2: residual chain once, B via global_load_lds ----
// 8 waves, 64 rows x 512 codes, BK=32. LDS 128KB: A_h/A_l full-K [64][256]
// (XOR-swizzled), B_h/B_l per-chunk [512][32] (pre-swizzled in global).
#define A_H_OFF 0
#define A_L_OFF 32768
#define B_H_OFF 65536
#define B_L_OFF 98304
#define SMEM_SZ 131072

__global__ __launch_bounds__(NTH) void gemm_top2_k(
    const float* __restrict__ data,
    const unsigned short* __restrict__ Ch_stage,
    const unsigned short* __restrict__ Cl_stage,
    const float* __restrict__ cbA, const float* __restrict__ cbB,
    const int* __restrict__ idxA, const int* __restrict__ idxB,
    const float* __restrict__ ccs, int stage,
    int* __restrict__ idx_out, unsigned int* __restrict__ flagcnt,
    int* __restrict__ flagrows) {
  __shared__ char smem[SMEM_SZ];

  const int tid = threadIdx.x;
  const int lane = tid & 63;
  const int w = tid >> 6;
  const int rowbase = blockIdx.x * MB;

  // ---- prologue: residual chain ONCE per row -> bf16 h/l into swizzled A tile
  for (int iter = 0; iter < 8; ++iter) {
    const int lr = iter * 8 + w;       // wave-uniform row
    const int r = rowbase + lr;
    const int k = lane * 4;
    float res[4];
    {
#pragma clang fp contract(off)
      const size_t base = (size_t)r * DDIM + k;
      float4 dv = *(const float4*)(data + base);
      float x1[4] = {dv.x, dv.y, dv.z, dv.w};
      if (stage == 0) {
#pragma unroll
        for (int j = 0; j < 4; ++j) res[j] = x1[j];
      } else {
        const int iA = idxA[r];
        float4 av = *(const float4*)(cbA + (size_t)iA * DDIM + k);
        float af[4] = {av.x, av.y, av.z, av.w};
        float a[4];
#pragma unroll
        for (int j = 0; j < 4; ++j) a[j] = x1[j] + (af[j] - x1[j]);
        if (stage == 2) {
          const int iB = idxB[r];
          float4 bv = *(const float4*)(cbB + (size_t)iB * DDIM + k);
          float bf[4] = {bv.x, bv.y, bv.z, bv.w};
#pragma unroll
          for (int j = 0; j < 4; ++j) {
            float x2 = x1[j] - a[j];
            float qst2 = x2 + (bf[j] - x2);
            a[j] = a[j] + qst2;
          }
        }
#pragma unroll
        for (int j = 0; j < 4; ++j) res[j] = x1[j] - a[j];
      }
    }
    unsigned short h4[4], l4[4];
#pragma unroll
    for (int j = 0; j < 4; ++j) {
      unsigned short h = f2bf(res[j]);
      h4[j] = h;
      l4[j] = f2bf(res[j] - bf2f(h));
    }
    const int byte = ((lr * 512 + (k >> 3) * 16) ^ ((lr & 7) << 4)) + ((k & 4) << 1);
    *(ushort4*)(smem + A_H_OFF + byte) = *(ushort4*)h4;
    *(ushort4*)(smem + A_L_OFF + byte) = *(ushort4*)l4;
  }

  f32x4 acc[4][4];
#pragma unroll
  for (int rt = 0; rt < 4; ++rt)
#pragma unroll
    for (int ct = 0; ct < 4; ++ct) {
      acc[rt][ct].x = 0.f; acc[rt][ct].y = 0.f;
      acc[rt][ct].z = 0.f; acc[rt][ct].w = 0.f;
    }

  const int g = lane >> 4, c16 = lane & 15;

  for (int chunk = 0; chunk < 8; ++chunk) {
    __syncthreads();  // prev chunk's B reads done (iter 0: A writes visible)
    {
      const char* gb = (const char*)Ch_stage + chunk * 32768 + w * 4096 + lane * 16;
      const char* gl = (const char*)Cl_stage + chunk * 32768 + w * 4096 + lane * 16;
      char* lb = smem + B_H_OFF + w * 4096;
      char* ll = smem + B_L_OFF + w * 4096;
#pragma unroll
      for (int j = 0; j < 4; ++j) {
        glds16(gb + j * 1024, lb + j * 1024);
        glds16(gl + j * 1024, ll + j * 1024);
      }
    }
    __syncthreads();  // drains vmcnt -> staged B visible

    short8v ah[4], al[4];
#pragma unroll
    for (int rt = 0; rt < 4; ++rt) {
      const int row = rt * 16 + c16;
      const int byte = (row * 512 + (chunk * 4 + g) * 16) ^ ((row & 7) << 4);
      ah[rt] = *(short8v*)(smem + A_H_OFF + byte);
      al[rt] = *(short8v*)(smem + A_L_OFF + byte);
    }
#pragma unroll
    for (int ct = 0; ct < 4; ++ct) {
      const int code = w * 64 + ct * 16 + c16;
      const int byte = (code * 64 + g * 16) ^ ((code & 7) << 4);
      short8v bh = *(short8v*)(smem + B_H_OFF + byte);
      short8v bl = *(short8v*)(smem + B_L_OFF + byte);
#pragma unroll
      for (int rt = 0; rt < 4; ++rt) {
        acc[rt][ct] = __builtin_amdgcn_mfma_f32_16x16x32_bf16(ah[rt], bh, acc[rt][ct], 0, 0, 0);
        acc[rt][ct] = __builtin_amdgcn_mfma_f32_16x16x32_bf16(ah[rt], bl, acc[rt][ct], 0, 0, 0);
        acc[rt][ct] = __builtin_amdgcn_mfma_f32_16x16x32_bf16(al[rt], bh, acc[rt][ct], 0, 0, 0);
      }
    }
  }
  __syncthreads();

  // ---- epilogue: d = cc - 2*dot, top-2 per row -> idx + flag
  float* red = (float*)(smem + B_H_OFF);  // [64 rows][8 waves][4 f32]
#pragma unroll
  for (int rt = 0; rt < 4; ++rt) {
#pragma unroll
    for (int reg = 0; reg < 4; ++reg) {
      const int row = rt * 16 + g * 4 + reg;
      float v1 = 3.0e38f, v2 = 3.0e38f;
      int i1 = 0x7fffffff;
#pragma unroll
      for (int ct = 0; ct < 4; ++ct) {
        const int col = w * 64 + ct * 16 + c16;
        float dd = ccs[col] - 2.0f * acc[rt][ct][reg];
        if (dd < v1 || (dd == v1 && col < i1)) { v2 = v1; v1 = dd; i1 = col; }
        else if (dd < v2) v2 = dd;
      }
#pragma unroll
      for (int m = 1; m < 16; m <<= 1) {
        float ov1 = __shfl_xor(v1, m, 64);
        int oi1 = __shfl_xor(i1, m, 64);
        float ov2 = __shfl_xor(v2, m, 64);
        float worst = fmaxf(v1, ov1);
        v2 = fminf(fminf(v2, ov2), worst);
        if (ov1 < v1 || (ov1 == v1 && oi1 < i1)) { v1 = ov1; i1 = oi1; }
      }
      if (c16 == 0) {
        float* slot = red + (size_t)(row * 8 + w) * 4;
        slot[0] = v1;
        ((int*)slot)[1] = i1;
        slot[2] = v2;
      }
    }
  }
  __syncthreads();
  if (tid < MB) {
    float v1 = 3.0e38f, v2 = 3.0e38f;
    int i1 = 0x7fffffff;
#pragma unroll
    for (int ww = 0; ww < 8; ++ww) {
      const float* slot = red + (size_t)(tid * 8 + ww) * 4;
      float ov1 = slot[0];
      int oi1 = ((const int*)slot)[1];
      float ov2 = slot[2];
      float worst = fmaxf(v1, ov1);
      v2 = fminf(fminf(v2, ov2), worst);
      if (ov1 < v1 || (ov1 == v1 && oi1 < i1)) { v1 = ov1; i1 = oi1; }
    }
    const int r = rowbase + tid;
    idx_out[r] = i1;
    if (v2 - v1 < MARGIN) {
      unsigned pos = atomicAdd(flagcnt, 1u);
      if (pos < MAXFLAG) flagrows[pos] = r;
    }
  }
}

// ---------------- np-bitwise refine for flagged rows (r12 PASS) ----------------
__global__ __launch_bounds__(256) void refine_k(
    const float* __restrict__ data, const float* __restrict__ cb,
    const float* __restrict__ cbA, const float* __restrict__ cbB,
    const int* __restrict__ idxA, const int* __restrict__ idxB,
    const float* __restrict__ ccs, int stage,
    const unsigned int* __restrict__ flagcnt, const int* __restrict__ flagrows,
    int* __restrict__ idx_out) {
  __shared__ float rl[DDIM];
  __shared__ float xxs;
  __shared__ float red_v[256];
  __shared__ int red_i[256];

  unsigned int n = *flagcnt;
  if (n > MAXFLAG) n = MAXFLAG;
  const int tid = threadIdx.x;

  for (unsigned f = blockIdx.x; f < n; f += gridDim.x) {
    const int r = flagrows[f];
    if (tid < 64) {
#pragma clang fp contract(off)
      const size_t base = (size_t)r * DDIM + tid * 4;
      float4 dv = *(const float4*)(data + base);
      float x1[4] = {dv.x, dv.y, dv.z, dv.w};
      float res[4];
      if (stage == 0) {
#pragma unroll
        for (int j = 0; j < 4; ++j) res[j] = x1[j];
      } else {
        const int iA = idxA[r];
        float4 av = *(const float4*)(cbA + (size_t)iA * DDIM + tid * 4);
        float af[4] = {av.x, av.y, av.z, av.w};
        float a[4];
#pragma unroll
        for (int j = 0; j < 4; ++j) a[j] = x1[j] + (af[j] - x1[j]);
        if (stage == 2) {
          const int iB = idxB[r];
          float4 bv = *(const float4*)(cbB + (size_t)iB * DDIM + tid * 4);
          float bf[4] = {bv.x, bv.y, bv.z, bv.w};
#pragma unroll
          for (int j = 0; j < 4; ++j) {
            float x2 = x1[j] - a[j];
            float qst2 = x2 + (bf[j] - x2);
            a[j] = a[j] + qst2;
          }
        }
#pragma unroll
        for (int j = 0; j < 4; ++j) res[j] = x1[j] - a[j];
      }
#pragma unroll
      for (int j = 0; j < 4; ++j) rl[tid * 4 + j] = res[j];
    }
    __syncthreads();
    if (tid == 0) xxs = np_sumsq256(rl);
    __syncthreads();

    float bv = 3.0e38f;
    int bi = 0x7fffffff;
#pragma unroll
    for (int h = 0; h < 2; ++h) {
      const int k = tid + h * 256;
      float d;
      {
#pragma clang fp contract(off)
        float dot = np_einsum_dot256(rl, cb + (size_t)k * DDIM);
        float t1 = xxs - 2.0f * dot;
        d = t1 + ccs[k];
      }
      if (d < bv || (d == bv && k < bi)) { bv = d; bi = k; }
    }
    red_v[tid] = bv;
    red_i[tid] = bi;
    __syncthreads();
    for (int sgap = 128; sgap > 0; sgap >>= 1) {
      if (tid < sgap) {
        float o = red_v[tid + sgap];
        int oi = red_i[tid + sgap];
        if (o < red_v[tid] || (o == red_v[tid] && oi < red_i[tid])) {
          red_v[tid] = o;
          red_i[tid] = oi;
        }
      }
      __syncthreads();
    }
    if (tid == 0) idx_out[r] = red_i[0];
    __syncthreads();
  }
}

// ---------------- final pass (r13: spread loss atomics) ----------------
__global__ __launch_bounds__(256) void final_k(
    const float* __restrict__ data, const float* __restrict__ cb0,
    const float* __restrict__ cb1, const float* __restrict__ cb2,
    const int* __restrict__ idx0, const int* __restrict__ idx1,
    const int* __restrict__ idx2, float* __restrict__ quant,
    float* __restrict__ enc0, float* __restrict__ enc1,
    float* __restrict__ enc2, double* __restrict__ loss_slots,
    unsigned int* __restrict__ hist) {
  __shared__ double wsum[4];
  const int lane = threadIdx.x & 63;
  const int w = threadIdx.x >> 6;
  const int r = blockIdx.x * 4 + w;
  const int i0 = idx0[r], i1 = idx1[r], i2 = idx2[r];
  const size_t base = (size_t)r * DDIM + lane * 4;
  float4 dv = *(const float4*)(data + base);
  float4 c0v = *(const float4*)(cb0 + (size_t)i0 * DDIM + lane * 4);
  float4 c1v = *(const float4*)(cb1 + (size_t)i1 * DDIM + lane * 4);
  float4 c2v = *(const float4*)(cb2 + (size_t)i2 * DDIM + lane * 4);
  float df[4] = {dv.x, dv.y, dv.z, dv.w};
  float q0f[4] = {c0v.x, c0v.y, c0v.z, c0v.w};
  float q1f[4] = {c1v.x, c1v.y, c1v.z, c1v.w};
  float q2f[4] = {c2v.x, c2v.y, c2v.z, c2v.w};
  float qout[4];
  double lsum = 0.0;
  {
#pragma clang fp contract(off)
#pragma unroll
    for (int j = 0; j < 4; ++j) {
      float x1 = df[j];
      float d1 = q0f[j] - x1;
      float qst1 = x1 + d1;
      float a1 = qst1;
      float x2 = x1 - a1;
      float d2 = q1f[j] - x2;
      float qst2 = x2 + d2;
      float a2 = a1 + qst2;
      float x3 = x1 - a2;
      float d3 = q2f[j] - x3;
      float qst3 = x3 + d3;
      float a3 = a2 + qst3;
      qout[j] = a3;
      lsum += (double)d1 * d1 + (double)d2 * d2 + (double)d3 * d3;
    }
  }
  float4 qv = {qout[0], qout[1], qout[2], qout[3]};
  *(float4*)(quant + base) = qv;

  const int kb = lane * 8;
  float* eptr[3] = {enc0, enc1, enc2};
  int eidx[3] = {i0, i1, i2};
#pragma unroll
  for (int e = 0; e < 3; ++e) {
    float4 u0, u1;
    u0.x = (kb + 0 == eidx[e]) ? 1.0f : 0.0f;
    u0.y = (kb + 1 == eidx[e]) ? 1.0f : 0.0f;
    u0.z = (kb + 2 == eidx[e]) ? 1.0f : 0.0f;
    u0.w = (kb + 3 == eidx[e]) ? 1.0f : 0.0f;
    u1.x = (kb + 4 == eidx[e]) ? 1.0f : 0.0f;
    u1.y = (kb + 5 == eidx[e]) ? 1.0f : 0.0f;
    u1.z = (kb + 6 == eidx[e]) ? 1.0f : 0.0f;
    u1.w = (kb + 7 == eidx[e]) ? 1.0f : 0.0f;
    float* dst = eptr[e] + (size_t)r * KCODES + kb;
    *(float4*)(dst) = u0;
    *(float4*)(dst + 4) = u1;
  }

#pragma unroll
  for (int off = 1; off < 64; off <<= 1) lsum += __shfl_xor(lsum, off, 64);
  if (lane == 0) {
    wsum[w] = lsum;
    atomicAdd(&hist[i0], 1u);
  } else if (lane == 1) {
    atomicAdd(&hist[KCODES + i1], 1u);
  } else if (lane == 2) {
    atomicAdd(&hist[2 * KCODES + i2], 1u);
  }
  __syncthreads();
  if (threadIdx.x == 0) {
    double bsum = (wsum[0] + wsum[1]) + (wsum[2] + wsum[3]);
    atomicAdd(&loss_slots[blockIdx.x & (NLOSS - 1)], bsum);
  }
}

// ---------------- scalars ----------------
__global__ void finalize_k(const unsigned int* __restrict__ hist,
                           const double* __restrict__ loss_slots,
                           float* __restrict__ out_scalars) {
  int lane = threadIdx.x;  // 64 threads
  double te = 0.0;
  for (int s = 0; s < NSTAGE; ++s) {
    double e = 0.0;
    for (int j = 0; j < KCODES / 64; ++j) {
      int k = j * 64 + lane;
      float pf = (float)hist[s * KCODES + k] * (1.0f / 65536.0f);
      float sf = __fadd_rn(pf, 1e-10f);
      e += (double)pf * log((double)sf);
    }
#pragma unroll
    for (int off = 1; off < 64; off <<= 1) e += __shfl_xor(e, off, 64);
    te += -e;
  }
  double ls = loss_slots[lane] + loss_slots[64 + lane] +
              loss_slots[128 + lane] + loss_slots[192 + lane];
#pragma unroll
  for (int off = 1; off < 64; off <<= 1) ls += __shfl_xor(ls, off, 64);
  if (lane == 0) {
    double tl = 1.25 * ls * (1.0 / 16777216.0);
    out_scalars[0] = (float)tl;
    out_scalars[1] = (float)te;
  }
}

extern "C" void kernel_launch(void* const* d_in, const int* in_sizes, int n_in,
                              void* d_out, int out_size, void* d_ws, size_t ws_size,
                              hipStream_t stream) {
  const float* data = (const float*)d_in[0];
  const float* cb0 = (const float*)d_in[1];
  const float* cb1 = (const float*)d_in[2];
  const float* cb2 = (const float*)d_in[3];
  const float* cbs[3] = {cb0, cb1, cb2};
  float* out = (float*)d_out;
  float* quant = out;
  float* enc0 = out + (size_t)NROWS * DDIM;
  float* enc1 = enc0 + (size_t)NROWS * KCODES;
  float* enc2 = enc1 + (size_t)NROWS * KCODES;
  float* out_scalars = enc2 + (size_t)NROWS * KCODES;

  // ws: [0) loss_slots f64x256 | 2048) hist u32x1536 | 8192) flagcnt u32x3 |
  //     8320) flagrows i32[3][8192] | 106688) cc f32x1536 | 112832) idx i32[3][N]
  //     | 899264) Ch swz-bf16 3x256KB | 1685696) Cl swz-bf16 3x256KB
  double* loss_slots = (double*)d_ws;
  unsigned int* hist = (unsigned int*)((char*)d_ws + 2048);
  unsigned int* flagcnt = (unsigned int*)((char*)d_ws + 8192);
  int* flagrows = (int*)((char*)d_ws + 8320);
  float* cc = (float*)((char*)d_ws + 106688);
  int* idx0 = (int*)((char*)d_ws + 112832);
  int* idx1 = idx0 + NROWS;
  int* idx2 = idx1 + NROWS;
  int* idxs[3] = {idx0, idx1, idx2};
  unsigned short* Ch = (unsigned short*)((char*)d_ws + 899264);
  unsigned short* Cl = (unsigned short*)((char*)d_ws + 1685696);

  hipMemsetAsync(d_ws, 0, 8320, stream);

  cc_np_k<<<(NSTAGE * KCODES + 255) / 256, 256, 0, stream>>>(cb0, cb1, cb2, cc);
  split_cb_k<<<(NSTAGE * KCODES * 32 + 255) / 256, 256, 0, stream>>>(
      cb0, cb1, cb2, Ch, Cl);

  for (int s = 0; s < NSTAGE; ++s) {
    gemm_top2_k<<<NROWS / MB, NTH, 0, stream>>>(
        data,
        (const unsigned short*)((char*)Ch + (size_t)s * 262144),
        (const unsigned short*)((char*)Cl + (size_t)s * 262144),
        cb0, cb1, idx0, idx1, cc + s * KCODES, s, idxs[s],
        flagcnt + s, flagrows + s * MAXFLAG);
    refine_k<<<128, 256, 0, stream>>>(
        data, cbs[s], cb0, cb1, idx0, idx1, cc + s * KCODES, s,
        flagcnt + s, flagrows + s * MAXFLAG, idxs[s]);
  }

  final_k<<<NROWS / 4, 256, 0, stream>>>(
      data, cb0, cb1, cb2, idx0, idx1, idx2, quant, enc0, enc1, enc2,
      loss_slots, hist);

  finalize_k<<<1, 64, 0, stream>>>(hist, loss_slots, out_scalars);
}

// Round 16
// 796.788 us; speedup vs baseline: 2.2865x; 1.0001x over previous
//
#include <hip/hip_runtime.h>
#include <math.h>

#define NROWS  65536
#define DDIM   256
#define KCODES 512
#define NTH    512
#define NSTAGE 3
#define MARGIN  2.5e-2f
#define MAXFLAG 8192
#define NLOSS   256
#define MB      64

typedef __attribute__((ext_vector_type(8))) short short8v;
typedef __attribute__((ext_vector_type(4))) float f32x4;

__device__ __forceinline__ unsigned short f2bf(float x) {
  unsigned int u = __float_as_uint(x);
  unsigned int r = (u + 0x7fffu + ((u >> 16) & 1u)) >> 16;
  return (unsigned short)r;
}
__device__ __forceinline__ float bf2f(unsigned short h) {
  return __uint_as_float(((unsigned int)h) << 16);
}

// ---- np.sum(x*x,-1) model: dispatched pairwise_sum, AVX512F (r12 PASS — do not touch)
__device__ __forceinline__ float np_sumsq256(const float* p) {
#pragma clang fp contract(off)
  float blk[2];
#pragma unroll
  for (int b = 0; b < 2; ++b) {
    const float* a = p + b * 128;
    float v[16];
#pragma unroll
    for (int l = 0; l < 16; ++l) {
      float p0a = a[l] * a[l];
      float p0b = a[64 + l] * a[64 + l];
      float P0 = p0a + p0b;
      float p1a = a[16 + l] * a[16 + l];
      float p1b = a[80 + l] * a[80 + l];
      float P1 = p1a + p1b;
      float p2a = a[32 + l] * a[32 + l];
      float p2b = a[96 + l] * a[96 + l];
      float P2 = p2a + p2b;
      float p3a = a[48 + l] * a[48 + l];
      float p3b = a[112 + l] * a[112 + l];
      float P3 = p3a + p3b;
      v[l] = (P0 + P1) + (P2 + P3);
    }
    float s1[8];
#pragma unroll
    for (int l = 0; l < 8; ++l) s1[l] = v[l] + v[l + 8];
    float s2[4];
#pragma unroll
    for (int l = 0; l < 4; ++l) s2[l] = s1[l] + s1[l + 4];
    float s3_0 = s2[0] + s2[2];
    float s3_1 = s2[1] + s2[3];
    blk[b] = s3_0 + s3_1;
  }
  return blk[0] + blk[1];
}

// ---- np c_einsum dot model: baseline SSE3 (r12 PASS — do not touch)
__device__ __forceinline__ float np_einsum_dot256(const float* __restrict__ x,
                                                  const float* __restrict__ c) {
#pragma clang fp contract(off)
  float v[4] = {0.f, 0.f, 0.f, 0.f};
  for (int t = 0; t < 16; ++t) {
    const float* a = x + t * 16;
    const float* b = c + t * 16;
#pragma unroll
    for (int l = 0; l < 4; ++l) {
      float ab3 = a[12 + l] * b[12 + l] + v[l];
      float ab2 = a[8 + l] * b[8 + l] + ab3;
      float ab1 = a[4 + l] * b[4 + l] + ab2;
      v[l] = a[0 + l] * b[0 + l] + ab1;
    }
  }
  return (v[0] + v[1]) + (v[2] + v[3]);
}

// ---------------- codebook norms, np-bitwise ----------------
__global__ void cc_np_k(const float* __restrict__ c0, const float* __restrict__ c1,
                        const float* __restrict__ c2, float* __restrict__ cc) {
  int t = blockIdx.x * blockDim.x + threadIdx.x;
  if (t >= NSTAGE * KCODES) return;
  const float* cb = (t < KCODES) ? c0 : (t < 2 * KCODES ? c1 : c2);
  cc[t] = np_sumsq256(cb + (size_t)(t & (KCODES - 1)) * DDIM);
}

// ---------------- split codebooks -> bf16 hi/lo, FRAGMENT-ORDERED global ----
// Per stage layout: [ctile 0..7][chunk 0..7][ct 0..3][lane 0..63] x 16B.
// Wave w's B fragment load for (chunk, ct) = ONE coalesced 1KB read at
// ((w*8+chunk)*4+ct)*1024 + lane*16.  lane = g*16 + c16; code = ctile*64+ct*16+c16;
// 16B = k [chunk*32+g*8, +8).
__global__ void split_cb_k(const float* __restrict__ c0, const float* __restrict__ c1,
                           const float* __restrict__ c2,
                           unsigned short* __restrict__ Ch,
                           unsigned short* __restrict__ Cl) {
  int t = blockIdx.x * 256 + threadIdx.x;
  if (t >= NSTAGE * KCODES * 32) return;
  int s = t / (KCODES * 32);
  int rem = t - s * KCODES * 32;
  int code = rem >> 5;
  int gran = rem & 31;          // k = gran*8
  int chunk = gran >> 2;
  int g = gran & 3;
  int ctile = code >> 6;
  int ct = (code >> 4) & 3;
  int c16 = code & 15;
  const float* cb = (s == 0) ? c0 : (s == 1 ? c1 : c2);
  const float* src = cb + (size_t)code * DDIM + gran * 8;
  unsigned short hv[8], lv[8];
#pragma unroll
  for (int j = 0; j < 8; ++j) {
    float x = src[j];
    unsigned short h = f2bf(x);
    hv[j] = h;
    lv[j] = f2bf(x - bf2f(h));
  }
  size_t off = (size_t)s * 262144 +
               ((((size_t)(ctile * 8 + chunk) * 4 + ct) * 64) + (g * 16 + c16)) * 16;
  *(uint4*)((char*)Ch + off) = *(uint4*)hv;
  *(uint4*)((char*)Cl + off) = *(uint4*)lv;
}

// ---------------- GEMM + top-2: A in LDS, B reg-loaded from L2, NO main-loop barriers ----
#define A_H_OFF 0
#define A_L_OFF 32768
#define RED_OFF 65536
#define SMEM_SZ 73728

__global__ __launch_bounds__(NTH) void gemm_top2_k(
    const float* __restrict__ data,
    const unsigned short* __restrict__ Chf,
    const unsigned short* __restrict__ Clf,
    const float* __restrict__ cbA, const float* __restrict__ cbB,
    const int* __restrict__ idxA, const int* __restrict__ idxB,
    const float* __restrict__ ccs, int stage,
    int* __restrict__ idx_out, unsigned int* __restrict__ flagcnt,
    int* __restrict__ flagrows) {
  __shared__ char smem[SMEM_SZ];

  const int tid = threadIdx.x;
  const int lane = tid & 63;
  const int w = tid >> 6;
  const int rowbase = blockIdx.x * MB;

  // ---- prologue: residual chain ONCE per row -> bf16 h/l into swizzled A tile
  for (int iter = 0; iter < 8; ++iter) {
    const int lr = iter * 8 + w;       // wave-uniform row
    const int r = rowbase + lr;
    const int k = lane * 4;
    float res[4];
    {
#pragma clang fp contract(off)
      const size_t base = (size_t)r * DDIM + k;
      float4 dv = *(const float4*)(data + base);
      float x1[4] = {dv.x, dv.y, dv.z, dv.w};
      if (stage == 0) {
#pragma unroll
        for (int j = 0; j < 4; ++j) res[j] = x1[j];
      } else {
        const int iA = idxA[r];
        float4 av = *(const float4*)(cbA + (size_t)iA * DDIM + k);
        float af[4] = {av.x, av.y, av.z, av.w};
        float a[4];
#pragma unroll
        for (int j = 0; j < 4; ++j) a[j] = x1[j] + (af[j] - x1[j]);
        if (stage == 2) {
          const int iB = idxB[r];
          float4 bv = *(const float4*)(cbB + (size_t)iB * DDIM + k);
          float bf[4] = {bv.x, bv.y, bv.z, bv.w};
#pragma unroll
          for (int j = 0; j < 4; ++j) {
            float x2 = x1[j] - a[j];
            float qst2 = x2 + (bf[j] - x2);
            a[j] = a[j] + qst2;
          }
        }
#pragma unroll
        for (int j = 0; j < 4; ++j) res[j] = x1[j] - a[j];
      }
    }
    unsigned short h4[4], l4[4];
#pragma unroll
    for (int j = 0; j < 4; ++j) {
      unsigned short h = f2bf(res[j]);
      h4[j] = h;
      l4[j] = f2bf(res[j] - bf2f(h));
    }
    const int byte = ((lr * 512 + (k >> 3) * 16) ^ ((lr & 7) << 4)) + ((k & 4) << 1);
    *(ushort4*)(smem + A_H_OFF + byte) = *(ushort4*)h4;
    *(ushort4*)(smem + A_L_OFF + byte) = *(ushort4*)l4;
  }

  f32x4 acc[4][4];
#pragma unroll
  for (int rt = 0; rt < 4; ++rt)
#pragma unroll
    for (int ct = 0; ct < 4; ++ct) {
      acc[rt][ct].x = 0.f; acc[rt][ct].y = 0.f;
      acc[rt][ct].z = 0.f; acc[rt][ct].w = 0.f;
    }

  const int g = lane >> 4, c16 = lane & 15;

  __syncthreads();   // A tile visible; ONLY barrier before epilogue

  for (int chunk = 0; chunk < 8; ++chunk) {
    short8v ah[4], al[4];
#pragma unroll
    for (int rt = 0; rt < 4; ++rt) {
      const int row = rt * 16 + c16;
      const int byte = (row * 512 + (chunk * 4 + g) * 16) ^ ((row & 7) << 4);
      ah[rt] = *(short8v*)(smem + A_H_OFF + byte);
      al[rt] = *(short8v*)(smem + A_L_OFF + byte);
    }
    const char* bh_base = (const char*)Chf + (size_t)((w * 8 + chunk) * 4) * 1024 + lane * 16;
    const char* bl_base = (const char*)Clf + (size_t)((w * 8 + chunk) * 4) * 1024 + lane * 16;
#pragma unroll
    for (int ct = 0; ct < 4; ++ct) {
      short8v bh = *(const short8v*)(bh_base + ct * 1024);
      short8v bl = *(const short8v*)(bl_base + ct * 1024);
#pragma unroll
      for (int rt = 0; rt < 4; ++rt) {
        acc[rt][ct] = __builtin_amdgcn_mfma_f32_16x16x32_bf16(ah[rt], bh, acc[rt][ct], 0, 0, 0);
        acc[rt][ct] = __builtin_amdgcn_mfma_f32_16x16x32_bf16(ah[rt], bl, acc[rt][ct], 0, 0, 0);
        acc[rt][ct] = __builtin_amdgcn_mfma_f32_16x16x32_bf16(al[rt], bh, acc[rt][ct], 0, 0, 0);
      }
    }
  }
  __syncthreads();   // A reads done; red buffer reuse safe

  // ---- epilogue: d = cc - 2*dot, top-2 per row -> idx + flag
  float* red = (float*)(smem + RED_OFF);  // [64 rows][8 waves][4 f32]
#pragma unroll
  for (int rt = 0; rt < 4; ++rt) {
#pragma unroll
    for (int reg = 0; reg < 4; ++reg) {
      const int row = rt * 16 + g * 4 + reg;
      float v1 = 3.0e38f, v2 = 3.0e38f;
      int i1 = 0x7fffffff;
#pragma unroll
      for (int ct = 0; ct < 4; ++ct) {
        const int col = w * 64 + ct * 16 + c16;
        float dd = ccs[col] - 2.0f * acc[rt][ct][reg];
        if (dd < v1 || (dd == v1 && col < i1)) { v2 = v1; v1 = dd; i1 = col; }
        else if (dd < v2) v2 = dd;
      }
#pragma unroll
      for (int m = 1; m < 16; m <<= 1) {
        float ov1 = __shfl_xor(v1, m, 64);
        int oi1 = __shfl_xor(i1, m, 64);
        float ov2 = __shfl_xor(v2, m, 64);
        float worst = fmaxf(v1, ov1);
        v2 = fminf(fminf(v2, ov2), worst);
        if (ov1 < v1 || (ov1 == v1 && oi1 < i1)) { v1 = ov1; i1 = oi1; }
      }
      if (c16 == 0) {
        float* slot = red + (size_t)(row * 8 + w) * 4;
        slot[0] = v1;
        ((int*)slot)[1] = i1;
        slot[2] = v2;
      }
    }
  }
  __syncthreads();
  if (tid < MB) {
    float v1 = 3.0e38f, v2 = 3.0e38f;
    int i1 = 0x7fffffff;
#pragma unroll
    for (int ww = 0; ww < 8; ++ww) {
      const float* slot = red + (size_t)(tid * 8 + ww) * 4;
      float ov1 = slot[0];
      int oi1 = ((const int*)slot)[1];
      float ov2 = slot[2];
      float worst = fmaxf(v1, ov1);
      v2 = fminf(fminf(v2, ov2), worst);
      if (ov1 < v1 || (ov1 == v1 && oi1 < i1)) { v1 = ov1; i1 = oi1; }
    }
    const int r = rowbase + tid;
    idx_out[r] = i1;
    if (v2 - v1 < MARGIN) {
      unsigned pos = atomicAdd(flagcnt, 1u);
      if (pos < MAXFLAG) flagrows[pos] = r;
    }
  }
}

// ---------------- np-bitwise refine for flagged rows (r12 PASS) ----------------
__global__ __launch_bounds__(256) void refine_k(
    const float* __restrict__ data, const float* __restrict__ cb,
    const float* __restrict__ cbA, const float* __restrict__ cbB,
    const int* __restrict__ idxA, const int* __restrict__ idxB,
    const float* __restrict__ ccs, int stage,
    const unsigned int* __restrict__ flagcnt, const int* __restrict__ flagrows,
    int* __restrict__ idx_out) {
  __shared__ float rl[DDIM];
  __shared__ float xxs;
  __shared__ float red_v[256];
  __shared__ int red_i[256];

  unsigned int n = *flagcnt;
  if (n > MAXFLAG) n = MAXFLAG;
  const int tid = threadIdx.x;

  for (unsigned f = blockIdx.x; f < n; f += gridDim.x) {
    const int r = flagrows[f];
    if (tid < 64) {
#pragma clang fp contract(off)
      const size_t base = (size_t)r * DDIM + tid * 4;
      float4 dv = *(const float4*)(data + base);
      float x1[4] = {dv.x, dv.y, dv.z, dv.w};
      float res[4];
      if (stage == 0) {
#pragma unroll
        for (int j = 0; j < 4; ++j) res[j] = x1[j];
      } else {
        const int iA = idxA[r];
        float4 av = *(const float4*)(cbA + (size_t)iA * DDIM + tid * 4);
        float af[4] = {av.x, av.y, av.z, av.w};
        float a[4];
#pragma unroll
        for (int j = 0; j < 4; ++j) a[j] = x1[j] + (af[j] - x1[j]);
        if (stage == 2) {
          const int iB = idxB[r];
          float4 bv = *(const float4*)(cbB + (size_t)iB * DDIM + tid * 4);
          float bf[4] = {bv.x, bv.y, bv.z, bv.w};
#pragma unroll
          for (int j = 0; j < 4; ++j) {
            float x2 = x1[j] - a[j];
            float qst2 = x2 + (bf[j] - x2);
            a[j] = a[j] + qst2;
          }
        }
#pragma unroll
        for (int j = 0; j < 4; ++j) res[j] = x1[j] - a[j];
      }
#pragma unroll
      for (int j = 0; j < 4; ++j) rl[tid * 4 + j] = res[j];
    }
    __syncthreads();
    if (tid == 0) xxs = np_sumsq256(rl);
    __syncthreads();

    float bv = 3.0e38f;
    int bi = 0x7fffffff;
#pragma unroll
    for (int h = 0; h < 2; ++h) {
      const int k = tid + h * 256;
      float d;
      {
#pragma clang fp contract(off)
        float dot = np_einsum_dot256(rl, cb + (size_t)k * DDIM);
        float t1 = xxs - 2.0f * dot;
        d = t1 + ccs[k];
      }
      if (d < bv || (d == bv && k < bi)) { bv = d; bi = k; }
    }
    red_v[tid] = bv;
    red_i[tid] = bi;
    __syncthreads();
    for (int sgap = 128; sgap > 0; sgap >>= 1) {
      if (tid < sgap) {
        float o = red_v[tid + sgap];
        int oi = red_i[tid + sgap];
        if (o < red_v[tid] || (o == red_v[tid] && oi < red_i[tid])) {
          red_v[tid] = o;
          red_i[tid] = oi;
        }
      }
      __syncthreads();
    }
    if (tid == 0) idx_out[r] = red_i[0];
    __syncthreads();
  }
}

// ---------------- slim final: quant + loss + hist + one-hot SCATTER ----
// enc zeros come from hipMemsetAsync (fill-rate ~7 TB/s); we only write the 1s.
__global__ __launch_bounds__(256) void final_k(
    const float* __restrict__ data, const float* __restrict__ cb0,
    const float* __restrict__ cb1, const float* __restrict__ cb2,
    const int* __restrict__ idx0, const int* __restrict__ idx1,
    const int* __restrict__ idx2, float* __restrict__ quant,
    float* __restrict__ enc0, float* __restrict__ enc1,
    float* __restrict__ enc2, double* __restrict__ loss_slots,
    unsigned int* __restrict__ hist) {
  __shared__ double wsum[4];
  const int lane = threadIdx.x & 63;
  const int w = threadIdx.x >> 6;
  const int r = blockIdx.x * 4 + w;
  const int i0 = idx0[r], i1 = idx1[r], i2 = idx2[r];
  const size_t base = (size_t)r * DDIM + lane * 4;
  float4 dv = *(const float4*)(data + base);
  float4 c0v = *(const float4*)(cb0 + (size_t)i0 * DDIM + lane * 4);
  float4 c1v = *(const float4*)(cb1 + (size_t)i1 * DDIM + lane * 4);
  float4 c2v = *(const float4*)(cb2 + (size_t)i2 * DDIM + lane * 4);
  float df[4] = {dv.x, dv.y, dv.z, dv.w};
  float q0f[4] = {c0v.x, c0v.y, c0v.z, c0v.w};
  float q1f[4] = {c1v.x, c1v.y, c1v.z, c1v.w};
  float q2f[4] = {c2v.x, c2v.y, c2v.z, c2v.w};
  float qout[4];
  double lsum = 0.0;
  {
#pragma clang fp contract(off)
#pragma unroll
    for (int j = 0; j < 4; ++j) {
      float x1 = df[j];
      float d1 = q0f[j] - x1;
      float qst1 = x1 + d1;
      float a1 = qst1;
      float x2 = x1 - a1;
      float d2 = q1f[j] - x2;
      float qst2 = x2 + d2;
      float a2 = a1 + qst2;
      float x3 = x1 - a2;
      float d3 = q2f[j] - x3;
      float qst3 = x3 + d3;
      float a3 = a2 + qst3;
      qout[j] = a3;
      lsum += (double)d1 * d1 + (double)d2 * d2 + (double)d3 * d3;
    }
  }
  float4 qv = {qout[0], qout[1], qout[2], qout[3]};
  *(float4*)(quant + base) = qv;

#pragma unroll
  for (int off = 1; off < 64; off <<= 1) lsum += __shfl_xor(lsum, off, 64);
  if (lane == 0) {
    wsum[w] = lsum;
    enc0[(size_t)r * KCODES + i0] = 1.0f;
    atomicAdd(&hist[i0], 1u);
  } else if (lane == 1) {
    enc1[(size_t)r * KCODES + i1] = 1.0f;
    atomicAdd(&hist[KCODES + i1], 1u);
  } else if (lane == 2) {
    enc2[(size_t)r * KCODES + i2] = 1.0f;
    atomicAdd(&hist[2 * KCODES + i2], 1u);
  }
  __syncthreads();
  if (threadIdx.x == 0) {
    double bsum = (wsum[0] + wsum[1]) + (wsum[2] + wsum[3]);
    atomicAdd(&loss_slots[blockIdx.x & (NLOSS - 1)], bsum);
  }
}

// ---------------- scalars ----------------
__global__ void finalize_k(const unsigned int* __restrict__ hist,
                           const double* __restrict__ loss_slots,
                           float* __restrict__ out_scalars) {
  int lane = threadIdx.x;  // 64 threads
  double te = 0.0;
  for (int s = 0; s < NSTAGE; ++s) {
    double e = 0.0;
    for (int j = 0; j < KCODES / 64; ++j) {
      int k = j * 64 + lane;
      float pf = (float)hist[s * KCODES + k] * (1.0f / 65536.0f);
      float sf = __fadd_rn(pf, 1e-10f);
      e += (double)pf * log((double)sf);
    }
#pragma unroll
    for (int off = 1; off < 64; off <<= 1) e += __shfl_xor(e, off, 64);
    te += -e;
  }
  double ls = loss_slots[lane] + loss_slots[64 + lane] +
              loss_slots[128 + lane] + loss_slots[192 + lane];
#pragma unroll
  for (int off = 1; off < 64; off <<= 1) ls += __shfl_xor(ls, off, 64);
  if (lane == 0) {
    double tl = 1.25 * ls * (1.0 / 16777216.0);
    out_scalars[0] = (float)tl;
    out_scalars[1] = (float)te;
  }
}

extern "C" void kernel_launch(void* const* d_in, const int* in_sizes, int n_in,
                              void* d_out, int out_size, void* d_ws, size_t ws_size,
                              hipStream_t stream) {
  const float* data = (const float*)d_in[0];
  const float* cb0 = (const float*)d_in[1];
  const float* cb1 = (const float*)d_in[2];
  const float* cb2 = (const float*)d_in[3];
  const float* cbs[3] = {cb0, cb1, cb2};
  float* out = (float*)d_out;
  float* quant = out;
  float* enc0 = out + (size_t)NROWS * DDIM;
  float* enc1 = enc0 + (size_t)NROWS * KCODES;
  float* enc2 = enc1 + (size_t)NROWS * KCODES;
  float* out_scalars = enc2 + (size_t)NROWS * KCODES;

  // ws: [0) loss_slots f64x256 | 2048) hist u32x1536 | 8192) flagcnt u32x3 |
  //     8320) flagrows i32[3][8192] | 106688) cc f32x1536 | 112832) idx i32[3][N]
  //     | 899264) Ch frag-bf16 3x256KB | 1685696) Cl frag-bf16 3x256KB
  double* loss_slots = (double*)d_ws;
  unsigned int* hist = (unsigned int*)((char*)d_ws + 2048);
  unsigned int* flagcnt = (unsigned int*)((char*)d_ws + 8192);
  int* flagrows = (int*)((char*)d_ws + 8320);
  float* cc = (float*)((char*)d_ws + 106688);
  int* idx0 = (int*)((char*)d_ws + 112832);
  int* idx1 = idx0 + NROWS;
  int* idx2 = idx1 + NROWS;
  int* idxs[3] = {idx0, idx1, idx2};
  unsigned short* Ch = (unsigned short*)((char*)d_ws + 899264);
  unsigned short* Cl = (unsigned short*)((char*)d_ws + 1685696);

  hipMemsetAsync(d_ws, 0, 8320, stream);
  // zero enc region at fill rate; final_k scatters the 1s
  hipMemsetAsync(enc0, 0, (size_t)3 * NROWS * KCODES * sizeof(float), stream);

  cc_np_k<<<(NSTAGE * KCODES + 255) / 256, 256, 0, stream>>>(cb0, cb1, cb2, cc);
  split_cb_k<<<(NSTAGE * KCODES * 32 + 255) / 256, 256, 0, stream>>>(
      cb0, cb1, cb2, Ch, Cl);

  for (int s = 0; s < NSTAGE; ++s) {
    gemm_top2_k<<<NROWS / MB, NTH, 0, stream>>>(
        data,
        (const unsigned short*)((char*)Ch + (size_t)s * 262144),
        (const unsigned short*)((char*)Cl + (size_t)s * 262144),
        cb0, cb1, idx0, idx1, cc + s * KCODES, s, idxs[s],
        flagcnt + s, flagrows + s * MAXFLAG);
    refine_k<<<128, 256, 0, stream>>>(
        data, cbs[s], cb0, cb1, idx0, idx1, cc + s * KCODES, s,
        flagcnt + s, flagrows + s * MAXFLAG, idxs[s]);
  }

  final_k<<<NROWS / 4, 256, 0, stream>>>(
      data, cb0, cb1, cb2, idx0, idx1, idx2, quant, enc0, enc1, enc2,
      loss_slots, hist);

  finalize_k<<<1, 64, 0, stream>>>(hist, loss_slots, out_scalars);
}